// Round 4
// baseline (249.711 us; speedup 1.0000x reference)
//
#include <hip/hip_runtime.h>
#include <hip/hip_bf16.h>
#include <cstdint>
#include <cstddef>

#define HID 128
#define DIM 64
#define ROWSV 8      // valid batch rows per block (2 blocks/CU)
#define NTILE 16     // MFMA N / LDS tile rows
#define TMAIN 512

typedef float f32x4 __attribute__((ext_vector_type(4)));
typedef short s16x8 __attribute__((ext_vector_type(8)));
typedef unsigned int u32x2 __attribute__((ext_vector_type(2)));

__device__ __forceinline__ unsigned short f2bf(float x){
    union { float f; unsigned int u; } v; v.f = x;
    unsigned int r = v.u + 0x7FFFu + ((v.u >> 16) & 1u);
    return (unsigned short)(r >> 16);
}
__device__ __forceinline__ float bf2f(unsigned short b){
    union { unsigned int u; float f; } v; v.u = ((unsigned int)b) << 16;
    return v.f;
}
__device__ __forceinline__ unsigned pk2(float a, float b){
    union { __hip_bfloat162 h; unsigned u; } cv;
    cv.h = __float22bfloat162_rn(make_float2(a, b));
    return cv.u;
}
__device__ __forceinline__ s16x8 mk8(unsigned a, unsigned b, unsigned c, unsigned d){
    union { s16x8 s; unsigned u[4]; } t; t.u[0]=a; t.u[1]=b; t.u[2]=c; t.u[3]=d; return t.s;
}
__device__ __forceinline__ s16x8 ldfrag_f32(const float* base){
    f32x4 a = *(const f32x4*)base;
    f32x4 b = *(const f32x4*)(base + 4);
    return mk8(pk2(a[0],a[1]), pk2(a[2],a[3]), pk2(b[0],b[1]), pk2(b[2],b[3]));
}

// workspace layout (bytes)
#define WS_MINV 0
#define WS_MHI  16384
#define WS_MLO  24576
#define WS_W1   32768
#define WS_W1T  49152
#define WS_W2   65536
#define WS_W2T  98304

// ---------------- kernel 1: block0 = invert M (swizzled GJ); block1 = bf16 weight prep ----------------
// aug stored swizzled: byte = r*512 + ((4*c) ^ ((r&7)<<4))  -> float4 col-slice ops are ~2-way.
__global__ __launch_bounds__(512) void k_prep(
    const float* __restrict__ L, const float* __restrict__ W1,
    const float* __restrict__ W2, char* __restrict__ ws)
{
    const int tid = threadIdx.x;
    if (blockIdx.x == 1){
        // ---- weight prep (parallel with inversion) ----
        unsigned short* w1b = (unsigned short*)(ws + WS_W1);
        unsigned short* w1t = (unsigned short*)(ws + WS_W1T);
        unsigned short* w2b = (unsigned short*)(ws + WS_W2);
        unsigned short* w2t = (unsigned short*)(ws + WS_W2T);
        for (int i = tid; i < HID*DIM; i += 512){
            float v = W1[i]; unsigned short b = f2bf(v);
            w1b[i] = b; int h = i >> 6, d = i & 63; w1t[d*HID + h] = b;
        }
        for (int i = tid; i < HID*HID; i += 512){
            float v = W2[i]; unsigned short b = f2bf(v);
            w2b[i] = b; int c2 = i >> 7, c1 = i & 127; w2t[c1*HID + c2] = b;
        }
        return;
    }
    __shared__ __align__(16) char augc[64*512];
    __shared__ float sL[64][65];
    #define AUGS(r,c) (*(float*)(augc + (r)*512 + ((4*(c)) ^ (((r)&7)<<4))))

    for (int i = tid; i < 64*64; i += 512)
        sL[i >> 6][i & 63] = L[i];
    __syncthreads();

    for (int e = tid; e < 64*64; e += 512){
        int r = e >> 6, c = e & 63;
        float acc = (r == c) ? 0.01f : 0.0f;
        #pragma unroll 8
        for (int k = 0; k < 64; ++k) acc += sL[r][k] * sL[c][k];
        AUGS(r, c) = acc;
        AUGS(r, 64+c) = (r == c) ? 1.0f : 0.0f;
    }

    const int c4B = (tid & 31) * 16;   // 16B col slice (byte offset)
    const int rb = tid >> 5;           // rows rb, rb+16, rb+32, rb+48
    for (int k = 0; k < 64; ++k){
        __syncthreads();
        float pivinv = 1.0f / AUGS(k, k);
        f32x4 piv = *(const f32x4*)(augc + k*512 + (c4B ^ ((k&7)<<4)));
        piv *= pivinv;
        float f[4]; f32x4 own[4];
        #pragma unroll
        for (int j = 0; j < 4; ++j){
            int r = rb + 16*j;
            f[j] = AUGS(r, k);
            own[j] = *(const f32x4*)(augc + r*512 + (c4B ^ ((r&7)<<4)));
        }
        __syncthreads();
        #pragma unroll
        for (int j = 0; j < 4; ++j){
            int r = rb + 16*j;
            f32x4 res = (r == k) ? piv : (own[j] - f[j] * piv);
            *(f32x4*)(augc + r*512 + (c4B ^ ((r&7)<<4))) = res;
        }
    }
    __syncthreads();

    float* minv = (float*)(ws + WS_MINV);
    unsigned short* mhi = (unsigned short*)(ws + WS_MHI);
    unsigned short* mlo = (unsigned short*)(ws + WS_MLO);
    for (int i = tid; i < 64*64; i += 512){
        float m = AUGS(i >> 6, 64 + (i & 63));
        minv[i] = m;
        unsigned short h = f2bf(m);
        mhi[i] = h;
        mlo[i] = f2bf(m - bf2f(h));
    }
    #undef AUGS
}

// ---------------- kernel 2: encoder + 64 leapfrog steps ----------------
__device__ __forceinline__ f32x4 mfma16(s16x8 a, s16x8 b, f32x4 c){
    return __builtin_amdgcn_mfma_f32_16x16x32_bf16(a, b, c, 0, 0, 0);
}

__global__ __launch_bounds__(TMAIN) void k_main(
    const float* __restrict__ z, const float* __restrict__ qW,
    const float* __restrict__ qb, const float* __restrict__ pW,
    const float* __restrict__ pb, const float* __restrict__ b1,
    const float* __restrict__ b2, const float* __restrict__ w3,
    const int* __restrict__ nsp, const char* __restrict__ ws,
    float* __restrict__ out, int B)
{
    __shared__ __align__(16) char sQ_[NTILE*256], sP_[NTILE*256];
    __shared__ __align__(16) char sQb_[NTILE*128], sPb_[NTILE*128];
    __shared__ __align__(16) char sA1_[NTILE*256], sG2_[NTILE*256], sG1_[NTILE*256];
    __shared__ __align__(16) char sD1_[NTILE*512];

    const int tid = threadIdx.x;
    const int w = tid >> 6, lane = tid & 63;
    const int l15 = lane & 15, l4 = lane >> 4;
    const int sw = (l15 & 7) << 4;
    const int m0 = w * 16;
    const int wq = w & 3;
    const int mq = wq * 16;
    const int NS = *nsp;
    const float dtv = 1.0f / (float)NS;
    const int TS = (NS + 1) * 128;
    const int b0 = blockIdx.x * ROWSV;
    const bool st_ok = (l15 < ROWSV);   // lanes 8-15 compute clamped-dup rows, never stored

    // ---- persistent weight A-fragments ----
    const unsigned short* wsW1  = (const unsigned short*)(ws + WS_W1);
    const unsigned short* wsW1T = (const unsigned short*)(ws + WS_W1T);
    const unsigned short* wsW2  = (const unsigned short*)(ws + WS_W2);
    const unsigned short* wsW2T = (const unsigned short*)(ws + WS_W2T);
    const unsigned short* wsMhi = (const unsigned short*)(ws + WS_MHI);
    const unsigned short* wsMlo = (const unsigned short*)(ws + WS_MLO);

    s16x8 fW1[2], fW2[4], fW2T[4];
    s16x8 fW1T[4] = {}, fMhi[2] = {}, fMlo[2] = {};
    #pragma unroll
    for (int kt = 0; kt < 2; ++kt)
        fW1[kt] = *(const s16x8*)&wsW1[(m0+l15)*DIM + kt*32 + 8*l4];
    #pragma unroll
    for (int kt = 0; kt < 4; ++kt){
        fW2[kt]  = *(const s16x8*)&wsW2 [(m0+l15)*HID + kt*32 + 8*l4];
        fW2T[kt] = *(const s16x8*)&wsW2T[(m0+l15)*HID + kt*32 + 8*l4];
    }
    if (w < 4){
        #pragma unroll
        for (int kt = 0; kt < 4; ++kt)
            fW1T[kt] = *(const s16x8*)&wsW1T[(mq+l15)*HID + kt*32 + 8*l4];
        #pragma unroll
        for (int kt = 0; kt < 2; ++kt){
            fMhi[kt] = *(const s16x8*)&wsMhi[(mq+l15)*DIM + kt*32 + 8*l4];
            fMlo[kt] = *(const s16x8*)&wsMlo[(mq+l15)*DIM + kt*32 + 8*l4];
        }
    }

    const f32x4 bb1 = *(const f32x4*)&b1[m0 + 4*l4];
    const f32x4 bb2 = *(const f32x4*)&b2[m0 + 4*l4];
    const f32x4 bw3 = *(const f32x4*)&w3[m0 + 4*l4];

    // ---- encoder ----
    {
        int brow = b0 + l15; if (brow >= B) brow = B - 1;
        const float* zr = z + (size_t)brow * DIM;
        s16x8 bz0 = ldfrag_f32(zr + 8*l4);
        s16x8 bz1 = ldfrag_f32(zr + 32 + 8*l4);
        const float* eW = (w < 4) ? qW : pW;
        const float* eb = (w < 4) ? qb : pb;
        const float* wr = eW + (size_t)(mq + l15) * DIM;
        s16x8 fE0 = ldfrag_f32(wr + 8*l4);
        s16x8 fE1 = ldfrag_f32(wr + 32 + 8*l4);
        f32x4 acc = {0.f,0.f,0.f,0.f};
        acc = mfma16(fE0, bz0, acc);
        acc = mfma16(fE1, bz1, acc);
        f32x4 be = *(const f32x4*)&eb[mq + 4*l4];
        f32x4 v = acc + be;
        char* sM  = (w < 4) ? sQ_ : sP_;
        char* sMb = (w < 4) ? sQb_ : sPb_;
        *(f32x4*)(sM + l15*256 + ((64*wq + 16*l4) ^ sw)) = v;
        u32x2 pr; pr[0] = pk2(v[0],v[1]); pr[1] = pk2(v[2],v[3]);
        *(u32x2*)(sMb + l15*128 + ((32*wq + 8*l4) ^ sw)) = pr;
        if (st_ok){
            const int ofs = (w < 4) ? (mq + 4*l4) : (64 + mq + 4*l4);
            *(f32x4*)(out + (size_t)(b0 + l15) * TS + ofs) = v;
        }
    }
    __syncthreads();

    f32x4 pend_qv = {0.f,0.f,0.f,0.f};   // q(t), stored at P1(t)
    f32x4 pend_ph = {0.f,0.f,0.f,0.f};   // p(t-1), stored at P1(t)

    for (int t = 0; t <= NS; ++t){
        // ---- Q: q += dt * Minv @ p_half (hi/lo split, 2 indep chains) ----
        if (t > 0){
            if (w < 4){
                f32x4 accH = {0.f,0.f,0.f,0.f}, accL = {0.f,0.f,0.f,0.f};
                #pragma unroll
                for (int kt = 0; kt < 2; ++kt){
                    s16x8 bp = *(const s16x8*)(sPb_ + l15*128 + ((64*kt + 16*l4) ^ sw));
                    accH = mfma16(fMhi[kt], bp, accH);
                    accL = mfma16(fMlo[kt], bp, accL);
                }
                f32x4* qp = (f32x4*)(sQ_ + l15*256 + ((64*wq + 16*l4) ^ sw));
                f32x4 qv = *qp;
                #pragma unroll
                for (int r = 0; r < 4; ++r) qv[r] += dtv * (accH[r] + accL[r]);
                *qp = qv;
                u32x2 pr; pr[0] = pk2(qv[0],qv[1]); pr[1] = pk2(qv[2],qv[3]);
                *(u32x2*)(sQb_ + l15*128 + ((32*wq + 8*l4) ^ sw)) = pr;
                pend_qv = qv;                      // deferred store (issued in P1)
            }
            __syncthreads();
        }
        // ---- P1: h1 = q@W1^T + b1 ; deferred traj stores issued here ----
        {
            if (w < 4 && st_ok && t >= 1){
                *(f32x4*)(out + (size_t)(b0+l15)*TS + (size_t)t*128 + mq + 4*l4) = pend_qv;
                if (t >= 2)
                    *(f32x4*)(out + (size_t)(b0+l15)*TS + (size_t)(t-1)*128 + 64 + mq + 4*l4) = pend_ph;
            }
            f32x4 a0 = {0.f,0.f,0.f,0.f}, a1v = {0.f,0.f,0.f,0.f};
            s16x8 bq0 = *(const s16x8*)(sQb_ + l15*128 + ((16*l4) ^ sw));
            s16x8 bq1 = *(const s16x8*)(sQb_ + l15*128 + ((64 + 16*l4) ^ sw));
            a0 = mfma16(fW1[0], bq0, a0);
            a1v = mfma16(fW1[1], bq1, a1v);
            f32x4 si, dv;
            #pragma unroll
            for (int r = 0; r < 4; ++r){
                float h = a0[r] + a1v[r] + bb1[r];
                float sg = 1.0f / (1.0f + __expf(-h));
                float s = h * sg;
                si[r] = s;
                dv[r] = sg + s * (1.0f - sg);
            }
            u32x2 pr; pr[0] = pk2(si[0],si[1]); pr[1] = pk2(si[2],si[3]);
            *(u32x2*)(sA1_ + l15*256 + ((2*m0 + 8*l4) ^ sw)) = pr;
            *(f32x4*)(sD1_ + l15*512 + ((4*m0 + 16*l4) ^ sw)) = dv;
        }
        __syncthreads();
        // ---- P2: h2 = a1@W2^T + b2 ; g2 = w3 * silu'(h2) ----
        {
            f32x4 a0 = {0.f,0.f,0.f,0.f}, a1v = {0.f,0.f,0.f,0.f};
            #pragma unroll
            for (int kt = 0; kt < 2; ++kt){
                s16x8 ba0 = *(const s16x8*)(sA1_ + l15*256 + ((64*(2*kt) + 16*l4) ^ sw));
                s16x8 ba1 = *(const s16x8*)(sA1_ + l15*256 + ((64*(2*kt+1) + 16*l4) ^ sw));
                a0 = mfma16(fW2[2*kt], ba0, a0);
                a1v = mfma16(fW2[2*kt+1], ba1, a1v);
            }
            f32x4 g2;
            #pragma unroll
            for (int r = 0; r < 4; ++r){
                float h = a0[r] + a1v[r] + bb2[r];
                float sg = 1.0f / (1.0f + __expf(-h));
                g2[r] = bw3[r] * (sg * (1.0f + h * (1.0f - sg)));
            }
            u32x2 pr; pr[0] = pk2(g2[0],g2[1]); pr[1] = pk2(g2[2],g2[3]);
            *(u32x2*)(sG2_ + l15*256 + ((2*m0 + 8*l4) ^ sw)) = pr;
        }
        __syncthreads();
        // ---- P3: g1 = (g2 @ W2) * d1 ----
        {
            f32x4 a0 = {0.f,0.f,0.f,0.f}, a1v = {0.f,0.f,0.f,0.f};
            #pragma unroll
            for (int kt = 0; kt < 2; ++kt){
                s16x8 bg0 = *(const s16x8*)(sG2_ + l15*256 + ((64*(2*kt) + 16*l4) ^ sw));
                s16x8 bg1 = *(const s16x8*)(sG2_ + l15*256 + ((64*(2*kt+1) + 16*l4) ^ sw));
                a0 = mfma16(fW2T[2*kt], bg0, a0);
                a1v = mfma16(fW2T[2*kt+1], bg1, a1v);
            }
            f32x4 dv = *(const f32x4*)(sD1_ + l15*512 + ((4*m0 + 16*l4) ^ sw));
            f32x4 g1;
            #pragma unroll
            for (int r = 0; r < 4; ++r) g1[r] = (a0[r] + a1v[r]) * dv[r];
            u32x2 pr; pr[0] = pk2(g1[0],g1[1]); pr[1] = pk2(g1[2],g1[3]);
            *(u32x2*)(sG1_ + l15*256 + ((2*m0 + 8*l4) ^ sw)) = pr;
        }
        __syncthreads();
        // ---- P4: grad = g1 @ W1 ; kicks ----
        if (w < 4){
            f32x4 a0 = {0.f,0.f,0.f,0.f}, a1v = {0.f,0.f,0.f,0.f};
            #pragma unroll
            for (int kt = 0; kt < 2; ++kt){
                s16x8 bg0 = *(const s16x8*)(sG1_ + l15*256 + ((64*(2*kt) + 16*l4) ^ sw));
                s16x8 bg1 = *(const s16x8*)(sG1_ + l15*256 + ((64*(2*kt+1) + 16*l4) ^ sw));
                a0 = mfma16(fW1T[2*kt], bg0, a0);
                a1v = mfma16(fW1T[2*kt+1], bg1, a1v);
            }
            f32x4* pp = (f32x4*)(sP_ + l15*256 + ((64*wq + 16*l4) ^ sw));
            f32x4 pv = *pp;
            if (t == 0){
                #pragma unroll
                for (int r = 0; r < 4; ++r) pv[r] -= 0.5f * dtv * (a0[r] + a1v[r]);
            } else {
                #pragma unroll
                for (int r = 0; r < 4; ++r){
                    float g = a0[r] + a1v[r];
                    pend_ph[r] = pv[r] - 0.5f * dtv * g;   // p(t), stored at P1(t+1)/post-loop
                    pv[r] -= dtv * g;
                }
            }
            *pp = pv;
            u32x2 pr; pr[0] = pk2(pv[0],pv[1]); pr[1] = pk2(pv[2],pv[3]);
            *(u32x2*)(sPb_ + l15*128 + ((32*wq + 8*l4) ^ sw)) = pr;
        }
        __syncthreads();
    }
    // flush last p-traj
    if (w < 4 && st_ok)
        *(f32x4*)(out + (size_t)(b0+l15)*TS + (size_t)NS*128 + 64 + mq + 4*l4) = pend_ph;
}

extern "C" void kernel_launch(void* const* d_in, const int* in_sizes, int n_in,
                              void* d_out, int out_size, void* d_ws, size_t ws_size,
                              hipStream_t stream)
{
    const float* z  = (const float*)d_in[0];
    const float* L  = (const float*)d_in[1];
    const float* W1 = (const float*)d_in[2];
    const float* b1 = (const float*)d_in[3];
    const float* W2 = (const float*)d_in[4];
    const float* b2 = (const float*)d_in[5];
    const float* w3 = (const float*)d_in[6];
    // d_in[7] = Vb3: constant, vanishes in gradV
    const float* qW = (const float*)d_in[8];
    const float* qb = (const float*)d_in[9];
    const float* pW = (const float*)d_in[10];
    const float* pb = (const float*)d_in[11];
    const int* nsp  = (const int*)d_in[12];
    float* out = (float*)d_out;
    char* ws = (char*)d_ws;
    const int B = in_sizes[0] / DIM;

    k_prep<<<2, 512, 0, stream>>>(L, W1, W2, ws);
    k_main<<<(B + ROWSV - 1)/ROWSV, TMAIN, 0, stream>>>(z, qW, qb, pW, pb, b1, b2, w3, nsp, ws, out, B);
}

// Round 5
// 201.509 us; speedup vs baseline: 1.2392x; 1.2392x over previous
//
#include <hip/hip_runtime.h>
#include <hip/hip_bf16.h>
#include <cstdint>
#include <cstddef>

#define HID 128
#define DIM 64
#define ROWS 16
#define TMAIN 512

typedef float f32x4 __attribute__((ext_vector_type(4)));
typedef short s16x8 __attribute__((ext_vector_type(8)));
typedef unsigned int u32x2 __attribute__((ext_vector_type(2)));

__device__ __forceinline__ unsigned short f2bf(float x){
    union { float f; unsigned int u; } v; v.f = x;
    unsigned int r = v.u + 0x7FFFu + ((v.u >> 16) & 1u);
    return (unsigned short)(r >> 16);
}
__device__ __forceinline__ float bf2f(unsigned short b){
    union { unsigned int u; float f; } v; v.u = ((unsigned int)b) << 16;
    return v.f;
}
__device__ __forceinline__ unsigned pk2(float a, float b){
    union { __hip_bfloat162 h; unsigned u; } cv;
    cv.h = __float22bfloat162_rn(make_float2(a, b));
    return cv.u;
}
__device__ __forceinline__ s16x8 mk8(unsigned a, unsigned b, unsigned c, unsigned d){
    union { s16x8 s; unsigned u[4]; } t; t.u[0]=a; t.u[1]=b; t.u[2]=c; t.u[3]=d; return t.s;
}
__device__ __forceinline__ s16x8 ldfrag_f32(const float* base){
    f32x4 a = *(const f32x4*)base;
    f32x4 b = *(const f32x4*)(base + 4);
    return mk8(pk2(a[0],a[1]), pk2(a[2],a[3]), pk2(b[0],b[1]), pk2(b[2],b[3]));
}

// workspace layout (bytes) — 131072 total
#define WS_W1MT 0          // bf16 [64][128]  (Minv @ W1^T)
#define WS_MHI  16384      // bf16 [64][64]   Minv hi (init only)
#define WS_MLO  24576      // bf16 [64][64]   Minv lo (init only)
#define WS_W1   32768      // bf16 [128][64]
#define WS_W1T  49152      // bf16 [64][128]
#define WS_W2   65536      // bf16 [128][128]
#define WS_W2T  98304      // bf16 [128][128]

// ---------------- kernel 1: block0 = invert M + W1MT; block1 = bf16 weight prep ----------------
// aug stored swizzled: byte = r*512 + ((4*c) ^ ((r&7)<<4)) -> float4 col-slice ops ~2-way.
__global__ __launch_bounds__(512) void k_prep(
    const float* __restrict__ L, const float* __restrict__ W1,
    const float* __restrict__ W2, char* __restrict__ ws)
{
    const int tid = threadIdx.x;
    if (blockIdx.x == 1){
        unsigned short* w1b = (unsigned short*)(ws + WS_W1);
        unsigned short* w1t = (unsigned short*)(ws + WS_W1T);
        unsigned short* w2b = (unsigned short*)(ws + WS_W2);
        unsigned short* w2t = (unsigned short*)(ws + WS_W2T);
        for (int i = tid; i < HID*DIM; i += 512){
            float v = W1[i]; unsigned short b = f2bf(v);
            w1b[i] = b; int h = i >> 6, d = i & 63; w1t[d*HID + h] = b;
        }
        for (int i = tid; i < HID*HID; i += 512){
            float v = W2[i]; unsigned short b = f2bf(v);
            w2b[i] = b; int c2 = i >> 7, c1 = i & 127; w2t[c1*HID + c2] = b;
        }
        return;
    }
    __shared__ __align__(16) char augc[64*512];
    __shared__ float sL[64][65];
    #define AUGS(r,c)  (*(float*)(augc + (r)*512 + ((4*(c)) ^ (((r)&7)<<4))))
    #define AUGS4(r,c) (*(const f32x4*)(augc + (r)*512 + ((4*(c)) ^ (((r)&7)<<4))))

    for (int i = tid; i < 64*64; i += 512)
        sL[i >> 6][i & 63] = L[i];
    __syncthreads();

    for (int e = tid; e < 64*64; e += 512){
        int r = e >> 6, c = e & 63;
        float acc = (r == c) ? 0.01f : 0.0f;
        #pragma unroll 8
        for (int k = 0; k < 64; ++k) acc += sL[r][k] * sL[c][k];
        AUGS(r, c) = acc;
        AUGS(r, 64+c) = (r == c) ? 1.0f : 0.0f;
    }

    const int c4B = (tid & 31) * 16;   // 16B col slice (byte offset)
    const int rb = tid >> 5;           // rows rb, rb+16, rb+32, rb+48
    for (int k = 0; k < 64; ++k){
        __syncthreads();
        float pivinv = 1.0f / AUGS(k, k);
        f32x4 piv = *(const f32x4*)(augc + k*512 + (c4B ^ ((k&7)<<4)));
        piv *= pivinv;
        float f[4]; f32x4 own[4];
        #pragma unroll
        for (int j = 0; j < 4; ++j){
            int r = rb + 16*j;
            f[j] = AUGS(r, k);
            own[j] = *(const f32x4*)(augc + r*512 + (c4B ^ ((r&7)<<4)));
        }
        __syncthreads();
        #pragma unroll
        for (int j = 0; j < 4; ++j){
            int r = rb + 16*j;
            f32x4 res = (r == k) ? piv : (own[j] - f[j] * piv);
            *(f32x4*)(augc + r*512 + (c4B ^ ((r&7)<<4))) = res;
        }
    }
    __syncthreads();

    // Minv hi/lo (used once for v-init)
    unsigned short* mhi = (unsigned short*)(ws + WS_MHI);
    unsigned short* mlo = (unsigned short*)(ws + WS_MLO);
    for (int i = tid; i < 64*64; i += 512){
        float m = AUGS(i >> 6, 64 + (i & 63));
        unsigned short h = f2bf(m);
        mhi[i] = h;
        mlo[i] = f2bf(m - bf2f(h));
    }

    // W1MT[d][h] = sum_e Minv[d][e] * W1[h][e]   (f32 math, bf16 store)
    {
        const int d = tid >> 3;
        const int h0 = (tid & 7) * 16;
        float acc[16];
        #pragma unroll
        for (int hh = 0; hh < 16; ++hh) acc[hh] = 0.0f;
        for (int e4 = 0; e4 < 16; ++e4){
            f32x4 m = AUGS4(d, 64 + 4*e4);
            #pragma unroll
            for (int hh = 0; hh < 16; ++hh){
                f32x4 wv4 = *(const f32x4*)(W1 + (size_t)(h0+hh)*DIM + 4*e4);
                acc[hh] += m[0]*wv4[0] + m[1]*wv4[1] + m[2]*wv4[2] + m[3]*wv4[3];
            }
        }
        unsigned short* w1mt = (unsigned short*)(ws + WS_W1MT);
        #pragma unroll
        for (int hh = 0; hh < 16; ++hh) w1mt[d*HID + h0 + hh] = f2bf(acc[hh]);
    }
    #undef AUGS
    #undef AUGS4
}

// ---------------- kernel 2: encoder + 64 leapfrog steps, 4 barriers/step ----------------
// State per block: q,v masters in waves 4-7 registers; p_half master in waves 0-3 registers.
// Per step: P1(h1,silu) -> P2 -> P3 -> P4{w<4: grad=g1@W1, p updates; w>=4: wv=g1@W1MT,
// v -= dt*wv, q += dt*v, write sQb}. Traj stores deferred to next P1 (no drain exposure).
__device__ __forceinline__ f32x4 mfma16(s16x8 a, s16x8 b, f32x4 c){
    return __builtin_amdgcn_mfma_f32_16x16x32_bf16(a, b, c, 0, 0, 0);
}

__global__ __launch_bounds__(TMAIN) void k_main(
    const float* __restrict__ z, const float* __restrict__ qW,
    const float* __restrict__ qb, const float* __restrict__ pW,
    const float* __restrict__ pb, const float* __restrict__ b1,
    const float* __restrict__ b2, const float* __restrict__ w3,
    const int* __restrict__ nsp, const char* __restrict__ ws,
    float* __restrict__ out)
{
    __shared__ __align__(16) char sQb_[ROWS*128], sPb_[ROWS*128];
    __shared__ __align__(16) char sA1_[ROWS*256], sG2_[ROWS*256], sG1_[ROWS*256];
    __shared__ __align__(16) char sD1_[ROWS*512];

    const int tid = threadIdx.x;
    const int w = tid >> 6, lane = tid & 63;
    const int l15 = lane & 15, l4 = lane >> 4;
    const int sw = (l15 & 7) << 4;
    const int m0 = w * 16;          // feature tile base (P1-P3)
    const int wq = w & 3;
    const int mq = wq * 16;         // dim tile base (P4 / enc / Vinit)
    const bool isQ = (w >= 4);      // waves 4-7 own q,v; waves 0-3 own p_half
    const int NS = *nsp;
    const float dtv = 1.0f / (float)NS;   // T_SPAN = (0,1)
    const int TS = (NS + 1) * 128;
    const int b0 = blockIdx.x * ROWS;

    // ---- persistent weight A-fragments ----
    const unsigned short* wsW1   = (const unsigned short*)(ws + WS_W1);
    const unsigned short* wsW1T  = (const unsigned short*)(ws + WS_W1T);
    const unsigned short* wsW1MT = (const unsigned short*)(ws + WS_W1MT);
    const unsigned short* wsW2   = (const unsigned short*)(ws + WS_W2);
    const unsigned short* wsW2T  = (const unsigned short*)(ws + WS_W2T);
    const unsigned short* wsMhi  = (const unsigned short*)(ws + WS_MHI);
    const unsigned short* wsMlo  = (const unsigned short*)(ws + WS_MLO);

    s16x8 fW1[2], fW2[4], fW2T[4];
    s16x8 fP4[4];                   // w<4: W1T tile; w>=4: W1MT tile
    s16x8 fMhi[2] = {}, fMlo[2] = {};
    #pragma unroll
    for (int kt = 0; kt < 2; ++kt)
        fW1[kt] = *(const s16x8*)&wsW1[(m0+l15)*DIM + kt*32 + 8*l4];
    #pragma unroll
    for (int kt = 0; kt < 4; ++kt){
        fW2[kt]  = *(const s16x8*)&wsW2 [(m0+l15)*HID + kt*32 + 8*l4];
        fW2T[kt] = *(const s16x8*)&wsW2T[(m0+l15)*HID + kt*32 + 8*l4];
    }
    {
        const unsigned short* wp4 = isQ ? wsW1MT : wsW1T;
        #pragma unroll
        for (int kt = 0; kt < 4; ++kt)
            fP4[kt] = *(const s16x8*)&wp4[(mq+l15)*HID + kt*32 + 8*l4];
    }
    if (isQ){
        #pragma unroll
        for (int kt = 0; kt < 2; ++kt){
            fMhi[kt] = *(const s16x8*)&wsMhi[(mq+l15)*DIM + kt*32 + 8*l4];
            fMlo[kt] = *(const s16x8*)&wsMlo[(mq+l15)*DIM + kt*32 + 8*l4];
        }
    }

    const f32x4 bb1 = *(const f32x4*)&b1[m0 + 4*l4];
    const f32x4 bb2 = *(const f32x4*)&b2[m0 + 4*l4];
    const f32x4 bw3 = *(const f32x4*)&w3[m0 + 4*l4];

    // ---- encoder: waves4-7 -> q0 (master+sQb), waves0-3 -> p0 (master) ----
    f32x4 master;                   // qm (isQ) or p_half (else); slice (row l15, dims mq+4l4..+3)
    {
        const float* zr = z + (size_t)(b0 + l15) * DIM;
        s16x8 bz0 = ldfrag_f32(zr + 8*l4);
        s16x8 bz1 = ldfrag_f32(zr + 32 + 8*l4);
        const float* eW = isQ ? qW : pW;
        const float* eb = isQ ? qb : pb;
        const float* wr = eW + (size_t)(mq + l15) * DIM;
        s16x8 fE0 = ldfrag_f32(wr + 8*l4);
        s16x8 fE1 = ldfrag_f32(wr + 32 + 8*l4);
        f32x4 acc = {0.f,0.f,0.f,0.f};
        acc = mfma16(fE0, bz0, acc);
        acc = mfma16(fE1, bz1, acc);
        f32x4 be = *(const f32x4*)&eb[mq + 4*l4];
        master = acc + be;
        if (isQ){
            u32x2 pr; pr[0] = pk2(master[0],master[1]); pr[1] = pk2(master[2],master[3]);
            *(u32x2*)(sQb_ + l15*128 + ((32*wq + 8*l4) ^ sw)) = pr;
        }
        const int ofs = isQ ? (mq + 4*l4) : (64 + mq + 4*l4);
        *(f32x4*)(out + (size_t)(b0 + l15) * TS + ofs) = master;
    }
    __syncthreads();

    f32x4 vm = {0.f,0.f,0.f,0.f};     // v = Minv @ p_half (waves 4-7)
    f32x4 pend = {0.f,0.f,0.f,0.f};   // pend_q (isQ) / pend_p (else)

    for (int t = 0; t <= NS; ++t){
        // ---- P1: deferred traj stores, then h1 = q@W1^T + b1 ----
        {
            if (t >= 1){
                if (isQ)
                    *(f32x4*)(out + (size_t)(b0+l15)*TS + (size_t)t*128 + mq + 4*l4) = pend;
                else if (t >= 2)
                    *(f32x4*)(out + (size_t)(b0+l15)*TS + (size_t)(t-1)*128 + 64 + mq + 4*l4) = pend;
            }
            s16x8 bq0 = *(const s16x8*)(sQb_ + l15*128 + ((16*l4) ^ sw));
            s16x8 bq1 = *(const s16x8*)(sQb_ + l15*128 + ((64 + 16*l4) ^ sw));
            f32x4 a0 = {0.f,0.f,0.f,0.f}, a1v = {0.f,0.f,0.f,0.f};
            a0 = mfma16(fW1[0], bq0, a0);
            a1v = mfma16(fW1[1], bq1, a1v);
            f32x4 si, dv;
            #pragma unroll
            for (int r = 0; r < 4; ++r){
                float h = a0[r] + a1v[r] + bb1[r];
                float sg = 1.0f / (1.0f + __expf(-h));
                float s = h * sg;
                si[r] = s;
                dv[r] = sg + s * (1.0f - sg);
            }
            u32x2 pr; pr[0] = pk2(si[0],si[1]); pr[1] = pk2(si[2],si[3]);
            *(u32x2*)(sA1_ + l15*256 + ((2*m0 + 8*l4) ^ sw)) = pr;
            *(f32x4*)(sD1_ + l15*512 + ((4*m0 + 16*l4) ^ sw)) = dv;
        }
        __syncthreads();
        // ---- P2: h2 = a1@W2^T + b2 ; g2 = w3 * silu'(h2) ----
        {
            f32x4 a0 = {0.f,0.f,0.f,0.f}, a1v = {0.f,0.f,0.f,0.f};
            #pragma unroll
            for (int kt = 0; kt < 2; ++kt){
                s16x8 ba0 = *(const s16x8*)(sA1_ + l15*256 + ((64*(2*kt) + 16*l4) ^ sw));
                s16x8 ba1 = *(const s16x8*)(sA1_ + l15*256 + ((64*(2*kt+1) + 16*l4) ^ sw));
                a0 = mfma16(fW2[2*kt], ba0, a0);
                a1v = mfma16(fW2[2*kt+1], ba1, a1v);
            }
            f32x4 g2;
            #pragma unroll
            for (int r = 0; r < 4; ++r){
                float h = a0[r] + a1v[r] + bb2[r];
                float sg = 1.0f / (1.0f + __expf(-h));
                g2[r] = bw3[r] * (sg * (1.0f + h * (1.0f - sg)));
            }
            u32x2 pr; pr[0] = pk2(g2[0],g2[1]); pr[1] = pk2(g2[2],g2[3]);
            *(u32x2*)(sG2_ + l15*256 + ((2*m0 + 8*l4) ^ sw)) = pr;
        }
        __syncthreads();
        // ---- P3: g1 = (g2 @ W2) * d1 ----
        {
            f32x4 a0 = {0.f,0.f,0.f,0.f}, a1v = {0.f,0.f,0.f,0.f};
            #pragma unroll
            for (int kt = 0; kt < 2; ++kt){
                s16x8 bg0 = *(const s16x8*)(sG2_ + l15*256 + ((64*(2*kt) + 16*l4) ^ sw));
                s16x8 bg1 = *(const s16x8*)(sG2_ + l15*256 + ((64*(2*kt+1) + 16*l4) ^ sw));
                a0 = mfma16(fW2T[2*kt], bg0, a0);
                a1v = mfma16(fW2T[2*kt+1], bg1, a1v);
            }
            f32x4 dv = *(const f32x4*)(sD1_ + l15*512 + ((4*m0 + 16*l4) ^ sw));
            f32x4 g1;
            #pragma unroll
            for (int r = 0; r < 4; ++r) g1[r] = (a0[r] + a1v[r]) * dv[r];
            u32x2 pr; pr[0] = pk2(g1[0],g1[1]); pr[1] = pk2(g1[2],g1[3]);
            *(u32x2*)(sG1_ + l15*256 + ((2*m0 + 8*l4) ^ sw)) = pr;
        }
        __syncthreads();
        // ---- P4: w<4: grad=g1@W1 -> p updates; w>=4: wv=g1@W1MT -> v,q updates ----
        if (!isQ){
            f32x4 a0 = {0.f,0.f,0.f,0.f}, a1v = {0.f,0.f,0.f,0.f};
            #pragma unroll
            for (int kt = 0; kt < 2; ++kt){
                s16x8 bg0 = *(const s16x8*)(sG1_ + l15*256 + ((64*(2*kt) + 16*l4) ^ sw));
                s16x8 bg1 = *(const s16x8*)(sG1_ + l15*256 + ((64*(2*kt+1) + 16*l4) ^ sw));
                a0 = mfma16(fP4[2*kt], bg0, a0);
                a1v = mfma16(fP4[2*kt+1], bg1, a1v);
            }
            if (t == 0){
                #pragma unroll
                for (int r = 0; r < 4; ++r) master[r] -= 0.5f * dtv * (a0[r] + a1v[r]);
                // publish p_half(1/2) as bf16 for the one-time v init
                u32x2 pr; pr[0] = pk2(master[0],master[1]); pr[1] = pk2(master[2],master[3]);
                *(u32x2*)(sPb_ + l15*128 + ((32*wq + 8*l4) ^ sw)) = pr;
            } else {
                #pragma unroll
                for (int r = 0; r < 4; ++r){
                    float g = a0[r] + a1v[r];
                    pend[r] = master[r] - 0.5f * dtv * g;   // p(t)
                    master[r] -= dtv * g;                    // p_half(t+1/2)
                }
            }
        } else if (t >= 1){
            f32x4 a0 = {0.f,0.f,0.f,0.f}, a1v = {0.f,0.f,0.f,0.f};
            #pragma unroll
            for (int kt = 0; kt < 2; ++kt){
                s16x8 bg0 = *(const s16x8*)(sG1_ + l15*256 + ((64*(2*kt) + 16*l4) ^ sw));
                s16x8 bg1 = *(const s16x8*)(sG1_ + l15*256 + ((64*(2*kt+1) + 16*l4) ^ sw));
                a0 = mfma16(fP4[2*kt], bg0, a0);
                a1v = mfma16(fP4[2*kt+1], bg1, a1v);
            }
            #pragma unroll
            for (int r = 0; r < 4; ++r){
                vm[r] -= dtv * (a0[r] + a1v[r]);   // v(t+1/2)
                master[r] += dtv * vm[r];          // q(t+1)
            }
            u32x2 pr; pr[0] = pk2(master[0],master[1]); pr[1] = pk2(master[2],master[3]);
            *(u32x2*)(sQb_ + l15*128 + ((32*wq + 8*l4) ^ sw)) = pr;
            pend = master;
        }
        __syncthreads();
        // ---- one-time v init after the first half-kick ----
        if (t == 0){
            if (isQ){
                s16x8 bp0 = *(const s16x8*)(sPb_ + l15*128 + ((16*l4) ^ sw));
                s16x8 bp1 = *(const s16x8*)(sPb_ + l15*128 + ((64 + 16*l4) ^ sw));
                f32x4 aH = {0.f,0.f,0.f,0.f}, aL = {0.f,0.f,0.f,0.f};
                aH = mfma16(fMhi[0], bp0, aH);
                aH = mfma16(fMhi[1], bp1, aH);
                aL = mfma16(fMlo[0], bp0, aL);
                aL = mfma16(fMlo[1], bp1, aL);
                #pragma unroll
                for (int r = 0; r < 4; ++r){
                    vm[r] = aH[r] + aL[r];         // v(1/2)
                    master[r] += dtv * vm[r];      // q(1)
                }
                u32x2 pr; pr[0] = pk2(master[0],master[1]); pr[1] = pk2(master[2],master[3]);
                *(u32x2*)(sQb_ + l15*128 + ((32*wq + 8*l4) ^ sw)) = pr;
                pend = master;
            }
            __syncthreads();
        }
    }
    // flush last p-traj
    if (!isQ)
        *(f32x4*)(out + (size_t)(b0+l15)*TS + (size_t)NS*128 + 64 + mq + 4*l4) = pend;
}

extern "C" void kernel_launch(void* const* d_in, const int* in_sizes, int n_in,
                              void* d_out, int out_size, void* d_ws, size_t ws_size,
                              hipStream_t stream)
{
    const float* z  = (const float*)d_in[0];
    const float* L  = (const float*)d_in[1];
    const float* W1 = (const float*)d_in[2];
    const float* b1 = (const float*)d_in[3];
    const float* W2 = (const float*)d_in[4];
    const float* b2 = (const float*)d_in[5];
    const float* w3 = (const float*)d_in[6];
    // d_in[7] = Vb3: constant, vanishes in gradV
    const float* qW = (const float*)d_in[8];
    const float* qb = (const float*)d_in[9];
    const float* pW = (const float*)d_in[10];
    const float* pb = (const float*)d_in[11];
    const int* nsp  = (const int*)d_in[12];
    float* out = (float*)d_out;
    char* ws = (char*)d_ws;
    const int B = in_sizes[0] / DIM;

    k_prep<<<2, 512, 0, stream>>>(L, W1, W2, ws);
    k_main<<<B/ROWS, TMAIN, 0, stream>>>(z, qW, qb, pW, pb, b1, b2, w3, nsp, ws, out);
}

// Round 6
// 166.460 us; speedup vs baseline: 1.5001x; 1.2106x over previous
//
#include <hip/hip_runtime.h>
#include <hip/hip_bf16.h>
#include <cstdint>
#include <cstddef>

#define HID 128
#define DIM 64
#define ROWS 16
#define TMAIN 512

typedef float f32x4 __attribute__((ext_vector_type(4)));
typedef short s16x8 __attribute__((ext_vector_type(8)));
typedef unsigned int u32x2 __attribute__((ext_vector_type(2)));

__device__ __forceinline__ unsigned short f2bf(float x){
    union { float f; unsigned int u; } v; v.f = x;
    unsigned int r = v.u + 0x7FFFu + ((v.u >> 16) & 1u);
    return (unsigned short)(r >> 16);
}
__device__ __forceinline__ float bf2f(unsigned short b){
    union { unsigned int u; float f; } v; v.u = ((unsigned int)b) << 16;
    return v.f;
}
__device__ __forceinline__ unsigned pk2(float a, float b){
    union { __hip_bfloat162 h; unsigned u; } cv;
    cv.h = __float22bfloat162_rn(make_float2(a, b));
    return cv.u;
}
__device__ __forceinline__ s16x8 mk8(unsigned a, unsigned b, unsigned c, unsigned d){
    union { s16x8 s; unsigned u[4]; } t; t.u[0]=a; t.u[1]=b; t.u[2]=c; t.u[3]=d; return t.s;
}
__device__ __forceinline__ s16x8 ldfrag_f32(const float* base){
    f32x4 a = *(const f32x4*)base;
    f32x4 b = *(const f32x4*)(base + 4);
    return mk8(pk2(a[0],a[1]), pk2(a[2],a[3]), pk2(b[0],b[1]), pk2(b[2],b[3]));
}
__device__ __forceinline__ f32x4 mfma16(s16x8 a, s16x8 b, f32x4 c){
    return __builtin_amdgcn_mfma_f32_16x16x32_bf16(a, b, c, 0, 0, 0);
}
// LDS-only barrier: skips the vmcnt(0) drain __syncthreads would force.
// Writer-side lgkmcnt(0) (+memory clobber) makes LDS writes visible; trailing
// compiler fence stops LDS reads hoisting above the s_barrier.
__device__ __forceinline__ void barrier_lds(){
    asm volatile("s_waitcnt lgkmcnt(0)" ::: "memory");
    __builtin_amdgcn_s_barrier();
    asm volatile("" ::: "memory");
}

// workspace layout (bytes) — 131072 total
#define WS_W1MT 0          // bf16 [64][128]  (Minv @ W1^T)
#define WS_MHI  16384      // bf16 [64][64]   Minv hi (t=0 v-init only)
#define WS_MLO  24576      // bf16 [64][64]   Minv lo
#define WS_W1   32768      // bf16 [128][64]
#define WS_W1T  49152      // bf16 [64][128]
#define WS_W2   65536      // bf16 [128][128]
#define WS_W2T  98304      // bf16 [128][128]

// ---------------- kernel 1: block0 = build M (global reads) + GJ invert + MFMA W1MT;
//                  block1 = bf16 weight prep ----------------
__global__ __launch_bounds__(512) void k_prep(
    const float* __restrict__ L, const float* __restrict__ W1,
    const float* __restrict__ W2, char* __restrict__ ws)
{
    const int tid = threadIdx.x;
    if (blockIdx.x == 1){
        unsigned short* w1b = (unsigned short*)(ws + WS_W1);
        unsigned short* w1t = (unsigned short*)(ws + WS_W1T);
        unsigned short* w2b = (unsigned short*)(ws + WS_W2);
        unsigned short* w2t = (unsigned short*)(ws + WS_W2T);
        for (int i = tid; i < HID*DIM; i += 512){
            float v = W1[i]; unsigned short b = f2bf(v);
            w1b[i] = b; int h = i >> 6, d = i & 63; w1t[d*HID + h] = b;
        }
        for (int i = tid; i < HID*HID; i += 512){
            float v = W2[i]; unsigned short b = f2bf(v);
            w2b[i] = b; int c2 = i >> 7, c1 = i & 127; w2t[c1*HID + c2] = b;
        }
        return;
    }
    __shared__ __align__(16) char augc[64*512];
    __shared__ __align__(16) unsigned short smh[64*64], sml[64*64];
    #define AUGS(r,c)  (*(float*)(augc + (r)*512 + ((4*(c)) ^ (((r)&7)<<4))))

    // ---- build augmented [M | I] straight from global L (f32x4 dot products) ----
    {
        const int r = tid >> 3, c0 = (tid & 7) * 8;
        f32x4 Lr[16];
        #pragma unroll
        for (int i = 0; i < 16; ++i) Lr[i] = *(const f32x4*)(L + r*64 + 4*i);
        #pragma unroll
        for (int cc = 0; cc < 8; ++cc){
            const int c = c0 + cc;
            const float* Lc = L + (size_t)c * 64;
            float acc = (r == c) ? 0.01f : 0.0f;
            #pragma unroll
            for (int i = 0; i < 16; ++i){
                f32x4 lc = *(const f32x4*)(Lc + 4*i);
                acc += Lr[i][0]*lc[0] + Lr[i][1]*lc[1] + Lr[i][2]*lc[2] + Lr[i][3]*lc[3];
            }
            AUGS(r, c) = acc;
            AUGS(r, 64+c) = (r == c) ? 1.0f : 0.0f;
        }
    }

    // ---- Gauss-Jordan (swizzled, conflict-free float4 column slices) ----
    const int c4B = (tid & 31) * 16;
    const int rb = tid >> 5;
    for (int k = 0; k < 64; ++k){
        barrier_lds();
        float pivinv = 1.0f / AUGS(k, k);
        f32x4 piv = *(const f32x4*)(augc + k*512 + (c4B ^ ((k&7)<<4)));
        piv *= pivinv;
        float f[4]; f32x4 own[4];
        #pragma unroll
        for (int j = 0; j < 4; ++j){
            int r = rb + 16*j;
            f[j] = AUGS(r, k);
            own[j] = *(const f32x4*)(augc + r*512 + (c4B ^ ((r&7)<<4)));
        }
        barrier_lds();
        #pragma unroll
        for (int j = 0; j < 4; ++j){
            int r = rb + 16*j;
            f32x4 res = (r == k) ? piv : (own[j] - f[j] * piv);
            *(f32x4*)(augc + r*512 + (c4B ^ ((r&7)<<4))) = res;
        }
    }
    barrier_lds();

    // ---- Minv hi/lo -> ws (for t=0 v-init) and LDS (for W1MT MFMA) ----
    unsigned short* mhi = (unsigned short*)(ws + WS_MHI);
    unsigned short* mlo = (unsigned short*)(ws + WS_MLO);
    for (int i = tid; i < 64*64; i += 512){
        float m = AUGS(i >> 6, 64 + (i & 63));
        unsigned short h = f2bf(m);
        unsigned short l = f2bf(m - bf2f(h));
        mhi[i] = h; mlo[i] = l;
        smh[i] = h; sml[i] = l;
    }
    barrier_lds();

    // ---- W1MT = Minv @ W1^T via MFMA (A = Mhi/Mlo tiles, B = W1 rows cast bf16) ----
    {
        const int lane = tid & 63;
        const int l15 = lane & 15, l4 = lane >> 4;
        const int h0 = (tid >> 6) * 16;          // wave -> 16 hidden features
        unsigned short* w1mt = (unsigned short*)(ws + WS_W1MT);
        #pragma unroll
        for (int d0 = 0; d0 < 64; d0 += 16){
            f32x4 acc = {0.f,0.f,0.f,0.f};
            #pragma unroll
            for (int kt = 0; kt < 2; ++kt){
                s16x8 fB = ldfrag_f32(W1 + (size_t)(h0+l15)*DIM + kt*32 + 8*l4);
                s16x8 aH = *(const s16x8*)&smh[(d0+l15)*DIM + kt*32 + 8*l4];
                s16x8 aL = *(const s16x8*)&sml[(d0+l15)*DIM + kt*32 + 8*l4];
                acc = mfma16(aH, fB, acc);
                acc = mfma16(aL, fB, acc);
            }
            #pragma unroll
            for (int r = 0; r < 4; ++r)
                w1mt[(size_t)(d0 + 4*l4 + r)*HID + h0 + l15] = f2bf(acc[r]);
        }
    }
    #undef AUGS
}

// ---------------- kernel 2: encoder + 64 leapfrog steps, 4 LDS-barriers/step ----------------
// waves 4-7 own q,v masters (registers); waves 0-3 own p_half. Traj stores issued at
// P1-start and drain in background (no vmcnt(0) barriers anywhere in the loop).
__global__ __launch_bounds__(TMAIN) void k_main(
    const float* __restrict__ z, const float* __restrict__ qW,
    const float* __restrict__ qb, const float* __restrict__ pW,
    const float* __restrict__ pb, const float* __restrict__ b1,
    const float* __restrict__ b2, const float* __restrict__ w3,
    const int* __restrict__ nsp, const char* __restrict__ ws,
    float* __restrict__ out)
{
    __shared__ __align__(16) char sQb_[ROWS*128], sPb_[ROWS*128];
    __shared__ __align__(16) char sA1_[ROWS*256], sG2_[ROWS*256], sG1_[ROWS*256];
    __shared__ __align__(16) char sD1_[ROWS*512];

    const int tid = threadIdx.x;
    const int w = tid >> 6, lane = tid & 63;
    const int l15 = lane & 15, l4 = lane >> 4;
    const int sw = (l15 & 7) << 4;
    const int m0 = w * 16;
    const int wq = w & 3;
    const int mq = wq * 16;
    const bool isQ = (w >= 4);
    const int NS = *nsp;
    const float dtv = 1.0f / (float)NS;   // T_SPAN = (0,1)
    const int TS = (NS + 1) * 128;
    const int b0 = blockIdx.x * ROWS;

    const unsigned short* wsW1   = (const unsigned short*)(ws + WS_W1);
    const unsigned short* wsW1T  = (const unsigned short*)(ws + WS_W1T);
    const unsigned short* wsW1MT = (const unsigned short*)(ws + WS_W1MT);
    const unsigned short* wsW2   = (const unsigned short*)(ws + WS_W2);
    const unsigned short* wsW2T  = (const unsigned short*)(ws + WS_W2T);
    const unsigned short* wsMhi  = (const unsigned short*)(ws + WS_MHI);
    const unsigned short* wsMlo  = (const unsigned short*)(ws + WS_MLO);

    s16x8 fW1[2], fW2[4], fW2T[4], fP4[4];
    #pragma unroll
    for (int kt = 0; kt < 2; ++kt)
        fW1[kt] = *(const s16x8*)&wsW1[(m0+l15)*DIM + kt*32 + 8*l4];
    #pragma unroll
    for (int kt = 0; kt < 4; ++kt){
        fW2[kt]  = *(const s16x8*)&wsW2 [(m0+l15)*HID + kt*32 + 8*l4];
        fW2T[kt] = *(const s16x8*)&wsW2T[(m0+l15)*HID + kt*32 + 8*l4];
    }
    {
        const unsigned short* wp4 = isQ ? wsW1MT : wsW1T;
        #pragma unroll
        for (int kt = 0; kt < 4; ++kt)
            fP4[kt] = *(const s16x8*)&wp4[(mq+l15)*HID + kt*32 + 8*l4];
    }

    const f32x4 bb1 = *(const f32x4*)&b1[m0 + 4*l4];
    const f32x4 bb2 = *(const f32x4*)&b2[m0 + 4*l4];
    const f32x4 bw3 = *(const f32x4*)&w3[m0 + 4*l4];

    // ---- encoder: waves4-7 -> q0, waves0-3 -> p0 (masters in registers) ----
    f32x4 master;
    {
        const float* zr = z + (size_t)(b0 + l15) * DIM;
        s16x8 bz0 = ldfrag_f32(zr + 8*l4);
        s16x8 bz1 = ldfrag_f32(zr + 32 + 8*l4);
        const float* eW = isQ ? qW : pW;
        const float* eb = isQ ? qb : pb;
        const float* wr = eW + (size_t)(mq + l15) * DIM;
        s16x8 fE0 = ldfrag_f32(wr + 8*l4);
        s16x8 fE1 = ldfrag_f32(wr + 32 + 8*l4);
        f32x4 acc = {0.f,0.f,0.f,0.f};
        acc = mfma16(fE0, bz0, acc);
        acc = mfma16(fE1, bz1, acc);
        f32x4 be = *(const f32x4*)&eb[mq + 4*l4];
        master = acc + be;
        if (isQ){
            u32x2 pr; pr[0] = pk2(master[0],master[1]); pr[1] = pk2(master[2],master[3]);
            *(u32x2*)(sQb_ + l15*128 + ((32*wq + 8*l4) ^ sw)) = pr;
        }
        const int ofs = isQ ? (mq + 4*l4) : (64 + mq + 4*l4);
        *(f32x4*)(out + (size_t)(b0 + l15) * TS + ofs) = master;
    }
    barrier_lds();

    f32x4 vm = {0.f,0.f,0.f,0.f};
    f32x4 pend = {0.f,0.f,0.f,0.f};

    for (int t = 0; t <= NS; ++t){
        // ---- P1: deferred traj stores, then h1 = q@W1^T + b1 ----
        {
            if (t >= 1){
                if (isQ)
                    *(f32x4*)(out + (size_t)(b0+l15)*TS + (size_t)t*128 + mq + 4*l4) = pend;
                else if (t >= 2)
                    *(f32x4*)(out + (size_t)(b0+l15)*TS + (size_t)(t-1)*128 + 64 + mq + 4*l4) = pend;
            }
            s16x8 bq0 = *(const s16x8*)(sQb_ + l15*128 + ((16*l4) ^ sw));
            s16x8 bq1 = *(const s16x8*)(sQb_ + l15*128 + ((64 + 16*l4) ^ sw));
            f32x4 a0 = {0.f,0.f,0.f,0.f}, a1v = {0.f,0.f,0.f,0.f};
            a0 = mfma16(fW1[0], bq0, a0);
            a1v = mfma16(fW1[1], bq1, a1v);
            f32x4 si, dv;
            #pragma unroll
            for (int r = 0; r < 4; ++r){
                float h = a0[r] + a1v[r] + bb1[r];
                float sg = 1.0f / (1.0f + __expf(-h));
                float s = h * sg;
                si[r] = s;
                dv[r] = sg + s * (1.0f - sg);
            }
            u32x2 pr; pr[0] = pk2(si[0],si[1]); pr[1] = pk2(si[2],si[3]);
            *(u32x2*)(sA1_ + l15*256 + ((2*m0 + 8*l4) ^ sw)) = pr;
            *(f32x4*)(sD1_ + l15*512 + ((4*m0 + 16*l4) ^ sw)) = dv;
        }
        barrier_lds();
        // ---- P2: h2 = a1@W2^T + b2 ; g2 = w3 * silu'(h2) ----
        {
            f32x4 a0 = {0.f,0.f,0.f,0.f}, a1v = {0.f,0.f,0.f,0.f};
            #pragma unroll
            for (int kt = 0; kt < 2; ++kt){
                s16x8 ba0 = *(const s16x8*)(sA1_ + l15*256 + ((64*(2*kt) + 16*l4) ^ sw));
                s16x8 ba1 = *(const s16x8*)(sA1_ + l15*256 + ((64*(2*kt+1) + 16*l4) ^ sw));
                a0 = mfma16(fW2[2*kt], ba0, a0);
                a1v = mfma16(fW2[2*kt+1], ba1, a1v);
            }
            f32x4 g2;
            #pragma unroll
            for (int r = 0; r < 4; ++r){
                float h = a0[r] + a1v[r] + bb2[r];
                float sg = 1.0f / (1.0f + __expf(-h));
                g2[r] = bw3[r] * (sg * (1.0f + h * (1.0f - sg)));
            }
            u32x2 pr; pr[0] = pk2(g2[0],g2[1]); pr[1] = pk2(g2[2],g2[3]);
            *(u32x2*)(sG2_ + l15*256 + ((2*m0 + 8*l4) ^ sw)) = pr;
        }
        barrier_lds();
        // ---- P3: g1 = (g2 @ W2) * d1 ----
        {
            f32x4 a0 = {0.f,0.f,0.f,0.f}, a1v = {0.f,0.f,0.f,0.f};
            #pragma unroll
            for (int kt = 0; kt < 2; ++kt){
                s16x8 bg0 = *(const s16x8*)(sG2_ + l15*256 + ((64*(2*kt) + 16*l4) ^ sw));
                s16x8 bg1 = *(const s16x8*)(sG2_ + l15*256 + ((64*(2*kt+1) + 16*l4) ^ sw));
                a0 = mfma16(fW2T[2*kt], bg0, a0);
                a1v = mfma16(fW2T[2*kt+1], bg1, a1v);
            }
            f32x4 dv = *(const f32x4*)(sD1_ + l15*512 + ((4*m0 + 16*l4) ^ sw));
            f32x4 g1;
            #pragma unroll
            for (int r = 0; r < 4; ++r) g1[r] = (a0[r] + a1v[r]) * dv[r];
            u32x2 pr; pr[0] = pk2(g1[0],g1[1]); pr[1] = pk2(g1[2],g1[3]);
            *(u32x2*)(sG1_ + l15*256 + ((2*m0 + 8*l4) ^ sw)) = pr;
        }
        barrier_lds();
        // ---- P4: w<4: grad=g1@W1 -> p; w>=4: wv=g1@W1MT -> v,q ----
        if (!isQ){
            f32x4 a0 = {0.f,0.f,0.f,0.f}, a1v = {0.f,0.f,0.f,0.f};
            #pragma unroll
            for (int kt = 0; kt < 2; ++kt){
                s16x8 bg0 = *(const s16x8*)(sG1_ + l15*256 + ((64*(2*kt) + 16*l4) ^ sw));
                s16x8 bg1 = *(const s16x8*)(sG1_ + l15*256 + ((64*(2*kt+1) + 16*l4) ^ sw));
                a0 = mfma16(fP4[2*kt], bg0, a0);
                a1v = mfma16(fP4[2*kt+1], bg1, a1v);
            }
            if (t == 0){
                #pragma unroll
                for (int r = 0; r < 4; ++r) master[r] -= 0.5f * dtv * (a0[r] + a1v[r]);
                u32x2 pr; pr[0] = pk2(master[0],master[1]); pr[1] = pk2(master[2],master[3]);
                *(u32x2*)(sPb_ + l15*128 + ((32*wq + 8*l4) ^ sw)) = pr;
            } else {
                #pragma unroll
                for (int r = 0; r < 4; ++r){
                    float g = a0[r] + a1v[r];
                    pend[r] = master[r] - 0.5f * dtv * g;   // p(t)
                    master[r] -= dtv * g;                    // p_half(t+1/2)
                }
            }
        } else if (t >= 1){
            f32x4 a0 = {0.f,0.f,0.f,0.f}, a1v = {0.f,0.f,0.f,0.f};
            #pragma unroll
            for (int kt = 0; kt < 2; ++kt){
                s16x8 bg0 = *(const s16x8*)(sG1_ + l15*256 + ((64*(2*kt) + 16*l4) ^ sw));
                s16x8 bg1 = *(const s16x8*)(sG1_ + l15*256 + ((64*(2*kt+1) + 16*l4) ^ sw));
                a0 = mfma16(fP4[2*kt], bg0, a0);
                a1v = mfma16(fP4[2*kt+1], bg1, a1v);
            }
            #pragma unroll
            for (int r = 0; r < 4; ++r){
                vm[r] -= dtv * (a0[r] + a1v[r]);   // v(t+1/2)
                master[r] += dtv * vm[r];          // q(t+1)
            }
            u32x2 pr; pr[0] = pk2(master[0],master[1]); pr[1] = pk2(master[2],master[3]);
            *(u32x2*)(sQb_ + l15*128 + ((32*wq + 8*l4) ^ sw)) = pr;
            pend = master;
        }
        barrier_lds();
        // ---- one-time v init after the first half-kick ----
        if (t == 0){
            if (isQ){
                s16x8 fMhi[2], fMlo[2];
                #pragma unroll
                for (int kt = 0; kt < 2; ++kt){
                    fMhi[kt] = *(const s16x8*)&wsMhi[(mq+l15)*DIM + kt*32 + 8*l4];
                    fMlo[kt] = *(const s16x8*)&wsMlo[(mq+l15)*DIM + kt*32 + 8*l4];
                }
                s16x8 bp0 = *(const s16x8*)(sPb_ + l15*128 + ((16*l4) ^ sw));
                s16x8 bp1 = *(const s16x8*)(sPb_ + l15*128 + ((64 + 16*l4) ^ sw));
                f32x4 aH = {0.f,0.f,0.f,0.f}, aL = {0.f,0.f,0.f,0.f};
                aH = mfma16(fMhi[0], bp0, aH);
                aH = mfma16(fMhi[1], bp1, aH);
                aL = mfma16(fMlo[0], bp0, aL);
                aL = mfma16(fMlo[1], bp1, aL);
                #pragma unroll
                for (int r = 0; r < 4; ++r){
                    vm[r] = aH[r] + aL[r];         // v(1/2)
                    master[r] += dtv * vm[r];      // q(1)
                }
                u32x2 pr; pr[0] = pk2(master[0],master[1]); pr[1] = pk2(master[2],master[3]);
                *(u32x2*)(sQb_ + l15*128 + ((32*wq + 8*l4) ^ sw)) = pr;
                pend = master;
            }
            barrier_lds();
        }
    }
    // flush last p-traj
    if (!isQ)
        *(f32x4*)(out + (size_t)(b0+l15)*TS + (size_t)NS*128 + 64 + mq + 4*l4) = pend;
}

extern "C" void kernel_launch(void* const* d_in, const int* in_sizes, int n_in,
                              void* d_out, int out_size, void* d_ws, size_t ws_size,
                              hipStream_t stream)
{
    const float* z  = (const float*)d_in[0];
    const float* L  = (const float*)d_in[1];
    const float* W1 = (const float*)d_in[2];
    const float* b1 = (const float*)d_in[3];
    const float* W2 = (const float*)d_in[4];
    const float* b2 = (const float*)d_in[5];
    const float* w3 = (const float*)d_in[6];
    // d_in[7] = Vb3: constant, vanishes in gradV
    const float* qW = (const float*)d_in[8];
    const float* qb = (const float*)d_in[9];
    const float* pW = (const float*)d_in[10];
    const float* pb = (const float*)d_in[11];
    const int* nsp  = (const int*)d_in[12];
    float* out = (float*)d_out;
    char* ws = (char*)d_ws;
    const int B = in_sizes[0] / DIM;

    k_prep<<<2, 512, 0, stream>>>(L, W1, W2, ws);
    k_main<<<B/ROWS, TMAIN, 0, stream>>>(z, qW, qb, pW, pb, b1, b2, w3, nsp, ws, out);
}

// Round 7
// 164.912 us; speedup vs baseline: 1.5142x; 1.0094x over previous
//
#include <hip/hip_runtime.h>
#include <hip/hip_bf16.h>
#include <cstdint>
#include <cstddef>

#define HID 128
#define DIM 64
#define ROWS 16
#define TMAIN 512

typedef float f32x4 __attribute__((ext_vector_type(4)));
typedef short s16x8 __attribute__((ext_vector_type(8)));
typedef unsigned int u32x2 __attribute__((ext_vector_type(2)));

__device__ __forceinline__ unsigned short f2bf(float x){
    union { float f; unsigned int u; } v; v.f = x;
    unsigned int r = v.u + 0x7FFFu + ((v.u >> 16) & 1u);
    return (unsigned short)(r >> 16);
}
__device__ __forceinline__ float bf2f(unsigned short b){
    union { unsigned int u; float f; } v; v.u = ((unsigned int)b) << 16;
    return v.f;
}
__device__ __forceinline__ unsigned pk2(float a, float b){
    union { __hip_bfloat162 h; unsigned u; } cv;
    cv.h = __float22bfloat162_rn(make_float2(a, b));
    return cv.u;
}
__device__ __forceinline__ s16x8 mk8(unsigned a, unsigned b, unsigned c, unsigned d){
    union { s16x8 s; unsigned u[4]; } t; t.u[0]=a; t.u[1]=b; t.u[2]=c; t.u[3]=d; return t.s;
}
// 8 consecutive f32 -> bf16 fragment
__device__ __forceinline__ s16x8 ldfrag_f32(const float* base){
    f32x4 a = *(const f32x4*)base;
    f32x4 b = *(const f32x4*)(base + 4);
    return mk8(pk2(a[0],a[1]), pk2(a[2],a[3]), pk2(b[0],b[1]), pk2(b[2],b[3]));
}
// 8 strided f32 (transposed weight column) -> bf16 fragment; reg j = p[j*stride]
__device__ __forceinline__ s16x8 ld_tr(const float* p, int stride){
    unsigned u[4];
    #pragma unroll
    for (int j = 0; j < 4; ++j){
        float a = p[(2*j)*stride];
        float b = p[(2*j+1)*stride];
        u[j] = pk2(a, b);
    }
    return mk8(u[0], u[1], u[2], u[3]);
}
__device__ __forceinline__ f32x4 mfma16(s16x8 a, s16x8 b, f32x4 c){
    return __builtin_amdgcn_mfma_f32_16x16x32_bf16(a, b, c, 0, 0, 0);
}
// LDS-only barrier: skips the vmcnt(0) drain __syncthreads would force.
__device__ __forceinline__ void barrier_lds(){
    asm volatile("s_waitcnt lgkmcnt(0)" ::: "memory");
    __builtin_amdgcn_s_barrier();
    asm volatile("" ::: "memory");
}

// ---------------- single fused kernel ----------------
// Per block: build M from L -> swizzled Gauss-Jordan (LDS, redundant per block,
// parallel wall-time) -> Mhi/Mlo + W1MT=Minv@W1^T via MFMA (LDS) -> weight frags
// straight from global f32 -> encoder -> 64 leapfrog steps (4 LDS-barriers/step,
// q/v and p masters in registers, traj stores drain in background).
// LDS map (64 KB): [0,24576) step tiles, aliased by [0,32768) GJ aug during prep;
// [32768,40960) Mhi; [40960,49152) Mlo; [49152,65536) W1MT.
__global__ __launch_bounds__(TMAIN) void k_main(
    const float* __restrict__ z, const float* __restrict__ L,
    const float* __restrict__ W1, const float* __restrict__ b1,
    const float* __restrict__ W2, const float* __restrict__ b2,
    const float* __restrict__ w3, const float* __restrict__ qW,
    const float* __restrict__ qb, const float* __restrict__ pW,
    const float* __restrict__ pb, const int* __restrict__ nsp,
    float* __restrict__ out)
{
    __shared__ __align__(16) char shm[65536];
    char* const sQb_ = shm;             // bf16 [16][64]   2048
    char* const sPb_ = shm + 2048;      // bf16 [16][64]   2048
    char* const sA1_ = shm + 4096;      // bf16 [16][128]  4096
    char* const sG2_ = shm + 8192;      // bf16 [16][128]  4096
    char* const sG1_ = shm + 12288;     // bf16 [16][128]  4096
    char* const sD1_ = shm + 16384;     // f32  [16][128]  8192 (end 24576)
    char* const augc = shm;             // f32 aug[64][128] swizzled, prep only
    unsigned short* const smh = (unsigned short*)(shm + 32768);
    unsigned short* const sml = (unsigned short*)(shm + 40960);
    unsigned short* const w1mt = (unsigned short*)(shm + 49152);

    const int tid = threadIdx.x;
    const int w = tid >> 6, lane = tid & 63;
    const int l15 = lane & 15, l4 = lane >> 4;
    const int sw = (l15 & 7) << 4;
    const int m0 = w * 16;          // feature tile base (P1-P3)
    const int wq = w & 3;
    const int mq = wq * 16;         // dim tile base (P4 / enc / v-init)
    const bool isQ = (w >= 4);
    const int NS = *nsp;
    const float dtv = 1.0f / (float)NS;   // T_SPAN = (0,1)
    const int TS = (NS + 1) * 128;
    const int b0 = blockIdx.x * ROWS;

    #define AUGS(r,c) (*(float*)(augc + (r)*512 + ((4*(c)) ^ (((r)&7)<<4))))

    // ---- build augmented [M | I], M = L L^T + 0.01 I (global f32x4 dots) ----
    {
        const int r = tid >> 3, c0 = (tid & 7) * 8;
        f32x4 Lr[16];
        #pragma unroll
        for (int i = 0; i < 16; ++i) Lr[i] = *(const f32x4*)(L + r*64 + 4*i);
        #pragma unroll
        for (int cc = 0; cc < 8; ++cc){
            const int c = c0 + cc;
            const float* Lc = L + (size_t)c * 64;
            float acc = (r == c) ? 0.01f : 0.0f;
            #pragma unroll
            for (int i = 0; i < 16; ++i){
                f32x4 lc = *(const f32x4*)(Lc + 4*i);
                acc += Lr[i][0]*lc[0] + Lr[i][1]*lc[1] + Lr[i][2]*lc[2] + Lr[i][3]*lc[3];
            }
            AUGS(r, c) = acc;
            AUGS(r, 64+c) = (r == c) ? 1.0f : 0.0f;
        }
    }

    // ---- Gauss-Jordan (swizzled, ~2-way conflicts, 2 barriers/pivot) ----
    {
        const int c4B = (tid & 31) * 16;
        const int rb = tid >> 5;
        for (int k = 0; k < 64; ++k){
            barrier_lds();
            float pivinv = 1.0f / AUGS(k, k);
            f32x4 piv = *(const f32x4*)(augc + k*512 + (c4B ^ ((k&7)<<4)));
            piv *= pivinv;
            float f[4]; f32x4 own[4];
            #pragma unroll
            for (int j = 0; j < 4; ++j){
                int r = rb + 16*j;
                f[j] = AUGS(r, k);
                own[j] = *(const f32x4*)(augc + r*512 + (c4B ^ ((r&7)<<4)));
            }
            barrier_lds();
            #pragma unroll
            for (int j = 0; j < 4; ++j){
                int r = rb + 16*j;
                f32x4 res = (r == k) ? piv : (own[j] - f[j] * piv);
                *(f32x4*)(augc + r*512 + (c4B ^ ((r&7)<<4))) = res;
            }
        }
    }
    barrier_lds();

    // ---- Minv hi/lo split into LDS ----
    for (int i = tid; i < 64*64; i += TMAIN){
        float m = AUGS(i >> 6, 64 + (i & 63));
        unsigned short h = f2bf(m);
        smh[i] = h;
        sml[i] = f2bf(m - bf2f(h));
    }
    barrier_lds();

    // ---- W1MT = Minv @ W1^T via MFMA (A = Mhi/Mlo, B = W1 rows from global) ----
    {
        const int h0 = w * 16;
        #pragma unroll
        for (int d0 = 0; d0 < 64; d0 += 16){
            f32x4 acc = {0.f,0.f,0.f,0.f};
            #pragma unroll
            for (int kt = 0; kt < 2; ++kt){
                s16x8 fB = ldfrag_f32(W1 + (size_t)(h0+l15)*DIM + kt*32 + 8*l4);
                s16x8 aH = *(const s16x8*)&smh[(d0+l15)*DIM + kt*32 + 8*l4];
                s16x8 aL = *(const s16x8*)&sml[(d0+l15)*DIM + kt*32 + 8*l4];
                acc = mfma16(aH, fB, acc);
                acc = mfma16(aL, fB, acc);
            }
            #pragma unroll
            for (int r = 0; r < 4; ++r)
                w1mt[(size_t)(d0 + 4*l4 + r)*HID + h0 + l15] = f2bf(acc[r]);
        }
    }
    barrier_lds();

    // ---- persistent weight A-fragments, straight from global f32 ----
    s16x8 fW1[2], fW2[4], fW2T[4], fP4[4];
    #pragma unroll
    for (int kt = 0; kt < 2; ++kt)
        fW1[kt] = ldfrag_f32(W1 + (size_t)(m0+l15)*DIM + kt*32 + 8*l4);
    #pragma unroll
    for (int kt = 0; kt < 4; ++kt){
        fW2[kt]  = ldfrag_f32(W2 + (size_t)(m0+l15)*HID + kt*32 + 8*l4);
        fW2T[kt] = ld_tr(W2 + (size_t)(kt*32 + 8*l4)*HID + m0 + l15, HID);
    }
    if (isQ){
        #pragma unroll
        for (int kt = 0; kt < 4; ++kt)
            fP4[kt] = *(const s16x8*)&w1mt[(mq+l15)*HID + kt*32 + 8*l4];
    } else {
        #pragma unroll
        for (int kt = 0; kt < 4; ++kt)
            fP4[kt] = ld_tr(W1 + (size_t)(kt*32 + 8*l4)*DIM + mq + l15, DIM);
    }

    const f32x4 bb1 = *(const f32x4*)&b1[m0 + 4*l4];
    const f32x4 bb2 = *(const f32x4*)&b2[m0 + 4*l4];
    const f32x4 bw3 = *(const f32x4*)&w3[m0 + 4*l4];

    // ---- encoder: waves4-7 -> q0, waves0-3 -> p0 (masters in registers) ----
    f32x4 master;
    {
        const float* zr = z + (size_t)(b0 + l15) * DIM;
        s16x8 bz0 = ldfrag_f32(zr + 8*l4);
        s16x8 bz1 = ldfrag_f32(zr + 32 + 8*l4);
        const float* eW = isQ ? qW : pW;
        const float* eb = isQ ? qb : pb;
        const float* wr = eW + (size_t)(mq + l15) * DIM;
        s16x8 fE0 = ldfrag_f32(wr + 8*l4);
        s16x8 fE1 = ldfrag_f32(wr + 32 + 8*l4);
        f32x4 acc = {0.f,0.f,0.f,0.f};
        acc = mfma16(fE0, bz0, acc);
        acc = mfma16(fE1, bz1, acc);
        f32x4 be = *(const f32x4*)&eb[mq + 4*l4];
        master = acc + be;
        if (isQ){
            u32x2 pr; pr[0] = pk2(master[0],master[1]); pr[1] = pk2(master[2],master[3]);
            *(u32x2*)(sQb_ + l15*128 + ((32*wq + 8*l4) ^ sw)) = pr;
        }
        const int ofs = isQ ? (mq + 4*l4) : (64 + mq + 4*l4);
        *(f32x4*)(out + (size_t)(b0 + l15) * TS + ofs) = master;
    }
    barrier_lds();

    f32x4 vm = {0.f,0.f,0.f,0.f};
    f32x4 pend = {0.f,0.f,0.f,0.f};

    for (int t = 0; t <= NS; ++t){
        // ---- P1: deferred traj stores, then h1 = q@W1^T + b1 ----
        {
            if (t >= 1){
                if (isQ)
                    *(f32x4*)(out + (size_t)(b0+l15)*TS + (size_t)t*128 + mq + 4*l4) = pend;
                else if (t >= 2)
                    *(f32x4*)(out + (size_t)(b0+l15)*TS + (size_t)(t-1)*128 + 64 + mq + 4*l4) = pend;
            }
            s16x8 bq0 = *(const s16x8*)(sQb_ + l15*128 + ((16*l4) ^ sw));
            s16x8 bq1 = *(const s16x8*)(sQb_ + l15*128 + ((64 + 16*l4) ^ sw));
            f32x4 a0 = {0.f,0.f,0.f,0.f}, a1v = {0.f,0.f,0.f,0.f};
            a0 = mfma16(fW1[0], bq0, a0);
            a1v = mfma16(fW1[1], bq1, a1v);
            f32x4 si, dv;
            #pragma unroll
            for (int r = 0; r < 4; ++r){
                float h = a0[r] + a1v[r] + bb1[r];
                float sg = 1.0f / (1.0f + __expf(-h));
                float s = h * sg;
                si[r] = s;
                dv[r] = sg + s * (1.0f - sg);
            }
            u32x2 pr; pr[0] = pk2(si[0],si[1]); pr[1] = pk2(si[2],si[3]);
            *(u32x2*)(sA1_ + l15*256 + ((2*m0 + 8*l4) ^ sw)) = pr;
            *(f32x4*)(sD1_ + l15*512 + ((4*m0 + 16*l4) ^ sw)) = dv;
        }
        barrier_lds();
        // ---- P2: h2 = a1@W2^T + b2 ; g2 = w3 * silu'(h2) ----
        {
            f32x4 a0 = {0.f,0.f,0.f,0.f}, a1v = {0.f,0.f,0.f,0.f};
            #pragma unroll
            for (int kt = 0; kt < 2; ++kt){
                s16x8 ba0 = *(const s16x8*)(sA1_ + l15*256 + ((64*(2*kt) + 16*l4) ^ sw));
                s16x8 ba1 = *(const s16x8*)(sA1_ + l15*256 + ((64*(2*kt+1) + 16*l4) ^ sw));
                a0 = mfma16(fW2[2*kt], ba0, a0);
                a1v = mfma16(fW2[2*kt+1], ba1, a1v);
            }
            f32x4 g2;
            #pragma unroll
            for (int r = 0; r < 4; ++r){
                float h = a0[r] + a1v[r] + bb2[r];
                float sg = 1.0f / (1.0f + __expf(-h));
                g2[r] = bw3[r] * (sg * (1.0f + h * (1.0f - sg)));
            }
            u32x2 pr; pr[0] = pk2(g2[0],g2[1]); pr[1] = pk2(g2[2],g2[3]);
            *(u32x2*)(sG2_ + l15*256 + ((2*m0 + 8*l4) ^ sw)) = pr;
        }
        barrier_lds();
        // ---- P3: g1 = (g2 @ W2) * d1 ----
        {
            f32x4 a0 = {0.f,0.f,0.f,0.f}, a1v = {0.f,0.f,0.f,0.f};
            #pragma unroll
            for (int kt = 0; kt < 2; ++kt){
                s16x8 bg0 = *(const s16x8*)(sG2_ + l15*256 + ((64*(2*kt) + 16*l4) ^ sw));
                s16x8 bg1 = *(const s16x8*)(sG2_ + l15*256 + ((64*(2*kt+1) + 16*l4) ^ sw));
                a0 = mfma16(fW2T[2*kt], bg0, a0);
                a1v = mfma16(fW2T[2*kt+1], bg1, a1v);
            }
            f32x4 dv = *(const f32x4*)(sD1_ + l15*512 + ((4*m0 + 16*l4) ^ sw));
            f32x4 g1;
            #pragma unroll
            for (int r = 0; r < 4; ++r) g1[r] = (a0[r] + a1v[r]) * dv[r];
            u32x2 pr; pr[0] = pk2(g1[0],g1[1]); pr[1] = pk2(g1[2],g1[3]);
            *(u32x2*)(sG1_ + l15*256 + ((2*m0 + 8*l4) ^ sw)) = pr;
        }
        barrier_lds();
        // ---- P4: w<4: grad=g1@W1 -> p; w>=4: wv=g1@W1MT -> v,q ----
        if (!isQ){
            f32x4 a0 = {0.f,0.f,0.f,0.f}, a1v = {0.f,0.f,0.f,0.f};
            #pragma unroll
            for (int kt = 0; kt < 2; ++kt){
                s16x8 bg0 = *(const s16x8*)(sG1_ + l15*256 + ((64*(2*kt) + 16*l4) ^ sw));
                s16x8 bg1 = *(const s16x8*)(sG1_ + l15*256 + ((64*(2*kt+1) + 16*l4) ^ sw));
                a0 = mfma16(fP4[2*kt], bg0, a0);
                a1v = mfma16(fP4[2*kt+1], bg1, a1v);
            }
            if (t == 0){
                #pragma unroll
                for (int r = 0; r < 4; ++r) master[r] -= 0.5f * dtv * (a0[r] + a1v[r]);
                u32x2 pr; pr[0] = pk2(master[0],master[1]); pr[1] = pk2(master[2],master[3]);
                *(u32x2*)(sPb_ + l15*128 + ((32*wq + 8*l4) ^ sw)) = pr;
            } else {
                #pragma unroll
                for (int r = 0; r < 4; ++r){
                    float g = a0[r] + a1v[r];
                    pend[r] = master[r] - 0.5f * dtv * g;   // p(t)
                    master[r] -= dtv * g;                    // p_half(t+1/2)
                }
            }
        } else if (t >= 1){
            f32x4 a0 = {0.f,0.f,0.f,0.f}, a1v = {0.f,0.f,0.f,0.f};
            #pragma unroll
            for (int kt = 0; kt < 2; ++kt){
                s16x8 bg0 = *(const s16x8*)(sG1_ + l15*256 + ((64*(2*kt) + 16*l4) ^ sw));
                s16x8 bg1 = *(const s16x8*)(sG1_ + l15*256 + ((64*(2*kt+1) + 16*l4) ^ sw));
                a0 = mfma16(fP4[2*kt], bg0, a0);
                a1v = mfma16(fP4[2*kt+1], bg1, a1v);
            }
            #pragma unroll
            for (int r = 0; r < 4; ++r){
                vm[r] -= dtv * (a0[r] + a1v[r]);   // v(t+1/2)
                master[r] += dtv * vm[r];          // q(t+1)
            }
            u32x2 pr; pr[0] = pk2(master[0],master[1]); pr[1] = pk2(master[2],master[3]);
            *(u32x2*)(sQb_ + l15*128 + ((32*wq + 8*l4) ^ sw)) = pr;
            pend = master;
        }
        barrier_lds();
        // ---- one-time v init after the first half-kick ----
        if (t == 0){
            if (isQ){
                s16x8 fMhi[2], fMlo[2];
                #pragma unroll
                for (int kt = 0; kt < 2; ++kt){
                    fMhi[kt] = *(const s16x8*)&smh[(mq+l15)*DIM + kt*32 + 8*l4];
                    fMlo[kt] = *(const s16x8*)&sml[(mq+l15)*DIM + kt*32 + 8*l4];
                }
                s16x8 bp0 = *(const s16x8*)(sPb_ + l15*128 + ((16*l4) ^ sw));
                s16x8 bp1 = *(const s16x8*)(sPb_ + l15*128 + ((64 + 16*l4) ^ sw));
                f32x4 aH = {0.f,0.f,0.f,0.f}, aL = {0.f,0.f,0.f,0.f};
                aH = mfma16(fMhi[0], bp0, aH);
                aH = mfma16(fMhi[1], bp1, aH);
                aL = mfma16(fMlo[0], bp0, aL);
                aL = mfma16(fMlo[1], bp1, aL);
                #pragma unroll
                for (int r = 0; r < 4; ++r){
                    vm[r] = aH[r] + aL[r];         // v(1/2)
                    master[r] += dtv * vm[r];      // q(1)
                }
                u32x2 pr; pr[0] = pk2(master[0],master[1]); pr[1] = pk2(master[2],master[3]);
                *(u32x2*)(sQb_ + l15*128 + ((32*wq + 8*l4) ^ sw)) = pr;
                pend = master;
            }
            barrier_lds();
        }
    }
    // flush last p-traj
    if (!isQ)
        *(f32x4*)(out + (size_t)(b0+l15)*TS + (size_t)NS*128 + 64 + mq + 4*l4) = pend;
    #undef AUGS
}

extern "C" void kernel_launch(void* const* d_in, const int* in_sizes, int n_in,
                              void* d_out, int out_size, void* d_ws, size_t ws_size,
                              hipStream_t stream)
{
    const float* z  = (const float*)d_in[0];
    const float* L  = (const float*)d_in[1];
    const float* W1 = (const float*)d_in[2];
    const float* b1 = (const float*)d_in[3];
    const float* W2 = (const float*)d_in[4];
    const float* b2 = (const float*)d_in[5];
    const float* w3 = (const float*)d_in[6];
    // d_in[7] = Vb3: constant, vanishes in gradV
    const float* qW = (const float*)d_in[8];
    const float* qb = (const float*)d_in[9];
    const float* pW = (const float*)d_in[10];
    const float* pb = (const float*)d_in[11];
    const int* nsp  = (const int*)d_in[12];
    float* out = (float*)d_out;
    (void)d_ws; (void)ws_size;
    const int B = in_sizes[0] / DIM;

    k_main<<<B/ROWS, TMAIN, 0, stream>>>(z, L, W1, b1, W2, b2, w3, qW, qb, pW, pb, nsp, out);
}

// Round 8
// 151.669 us; speedup vs baseline: 1.6464x; 1.0873x over previous
//
#include <hip/hip_runtime.h>
#include <hip/hip_bf16.h>
#include <cstdint>
#include <cstddef>

#define HID 128
#define DIM 64
#define ROWS 16
#define TMAIN 512

typedef float f32x4 __attribute__((ext_vector_type(4)));
typedef short s16x8 __attribute__((ext_vector_type(8)));
typedef unsigned int u32x2 __attribute__((ext_vector_type(2)));

__device__ __forceinline__ unsigned short f2bf(float x){
    union { float f; unsigned int u; } v; v.f = x;
    unsigned int r = v.u + 0x7FFFu + ((v.u >> 16) & 1u);
    return (unsigned short)(r >> 16);
}
__device__ __forceinline__ float bf2f(unsigned short b){
    union { unsigned int u; float f; } v; v.u = ((unsigned int)b) << 16;
    return v.f;
}
__device__ __forceinline__ unsigned pk2(float a, float b){
    union { __hip_bfloat162 h; unsigned u; } cv;
    cv.h = __float22bfloat162_rn(make_float2(a, b));
    return cv.u;
}
__device__ __forceinline__ s16x8 mk8(unsigned a, unsigned b, unsigned c, unsigned d){
    union { s16x8 s; unsigned u[4]; } t; t.u[0]=a; t.u[1]=b; t.u[2]=c; t.u[3]=d; return t.s;
}
// 8 consecutive f32 -> bf16 fragment
__device__ __forceinline__ s16x8 ldfrag_f32(const float* base){
    f32x4 a = *(const f32x4*)base;
    f32x4 b = *(const f32x4*)(base + 4);
    return mk8(pk2(a[0],a[1]), pk2(a[2],a[3]), pk2(b[0],b[1]), pk2(b[2],b[3]));
}
// 8 consecutive f32 -> hi/lo bf16 fragment pair (hi = RNE(x), lo = RNE(x - hi))
__device__ __forceinline__ void ldfrag_hl(const float* base, s16x8& hi, s16x8& lo){
    f32x4 a = *(const f32x4*)base;
    f32x4 b = *(const f32x4*)(base + 4);
    float x[8] = {a[0],a[1],a[2],a[3],b[0],b[1],b[2],b[3]};
    union { s16x8 s; unsigned short us[8]; } H, L;
    #pragma unroll
    for (int j = 0; j < 8; ++j){
        unsigned short h = f2bf(x[j]);
        H.us[j] = h;
        L.us[j] = f2bf(x[j] - bf2f(h));
    }
    hi = H.s; lo = L.s;
}
// 8 strided f32 (transposed weight column) -> bf16 fragment
__device__ __forceinline__ s16x8 ld_tr(const float* p, int stride){
    unsigned u[4];
    #pragma unroll
    for (int j = 0; j < 4; ++j){
        float a = p[(2*j)*stride];
        float b = p[(2*j+1)*stride];
        u[j] = pk2(a, b);
    }
    return mk8(u[0], u[1], u[2], u[3]);
}
__device__ __forceinline__ f32x4 mfma16(s16x8 a, s16x8 b, f32x4 c){
    return __builtin_amdgcn_mfma_f32_16x16x32_bf16(a, b, c, 0, 0, 0);
}
// split f32x4 into hi/lo bf16 and store 8B each into buf (hi) and buf+8192 (lo)
__device__ __forceinline__ void wr_hl(char* buf, int off, f32x4 v){
    unsigned short h[4], l[4];
    #pragma unroll
    for (int r = 0; r < 4; ++r){
        h[r] = f2bf(v[r]);
        l[r] = f2bf(v[r] - bf2f(h[r]));
    }
    u32x2 H, L;
    H[0] = (unsigned)h[0] | ((unsigned)h[1] << 16);
    H[1] = (unsigned)h[2] | ((unsigned)h[3] << 16);
    L[0] = (unsigned)l[0] | ((unsigned)l[1] << 16);
    L[1] = (unsigned)l[2] | ((unsigned)l[3] << 16);
    *(u32x2*)(buf + off) = H;
    *(u32x2*)(buf + 8192 + off) = L;
}
// LDS-only barrier: skips the vmcnt(0) drain __syncthreads would force.
__device__ __forceinline__ void barrier_lds(){
    asm volatile("s_waitcnt lgkmcnt(0)" ::: "memory");
    __builtin_amdgcn_s_barrier();
    asm volatile("" ::: "memory");
}

// ---------------- single fused kernel ----------------
// Prep per block (redundant, parallel wall-time), all MFMA-based:
//   M = L L^T + 0.01 I  (hi/lo 3-term MFMA from global L)  -> bufC (transposed, swizzled)
//   c = 0.995 / max row sum |M|  (Gershgorin)  ->  X0 = c I
//   Newton-Schulz x12: Y = M X ; X' = 2X - Y^T X   (all stored transposed,
//   hi/lo bf16 pairs, 3-term MFMA, 2 LDS barriers/iter, 3 rotating 16KB buffers)
//   Minv := X -> smh/sml ; W1MT = Minv @ W1^T via MFMA.
// Then: weight frags from global f32 -> encoder -> 64 leapfrog steps
// (4 LDS-barriers/step, q/v and p masters in registers, deferred traj stores).
// LDS map (64 KB): [0,16K) bufA / step tiles; [16K,32K) bufB / step tiles;
// [32K,48K) bufC = M, Newton rotation, then Minv hi/lo; [48K,64K) rowsum scratch then W1MT.
__global__ __launch_bounds__(TMAIN) void k_main(
    const float* __restrict__ z, const float* __restrict__ L,
    const float* __restrict__ W1, const float* __restrict__ b1,
    const float* __restrict__ W2, const float* __restrict__ b2,
    const float* __restrict__ w3, const float* __restrict__ qW,
    const float* __restrict__ qb, const float* __restrict__ pW,
    const float* __restrict__ pb, const int* __restrict__ nsp,
    float* __restrict__ out)
{
    __shared__ __align__(16) char shm[65536];
    char* const sQb_ = shm;             // bf16 [16][64]   2048
    char* const sPb_ = shm + 2048;      // bf16 [16][64]   2048
    char* const sA1_ = shm + 4096;      // bf16 [16][128]  4096
    char* const sG2_ = shm + 8192;      // bf16 [16][128]  4096
    char* const sG1_ = shm + 12288;     // bf16 [16][128]  4096
    char* const sD1_ = shm + 16384;     // f32  [16][128]  8192 (end 24576)
    char* const bufA = shm;             // Newton scratch (prep only)
    char* const bufB = shm + 16384;
    char* const bufC = shm + 32768;     // M -> rotation -> Minv hi/lo
    unsigned short* const smh = (unsigned short*)(shm + 32768);
    unsigned short* const sml = (unsigned short*)(shm + 40960);
    unsigned short* const w1mt = (unsigned short*)(shm + 49152);
    float* const fscr = (float*)(shm + 49152);   // rowsum scratch (pre-W1MT)

    const int tid = threadIdx.x;
    const int w = tid >> 6, lane = tid & 63;
    const int l15 = lane & 15, l4 = lane >> 4;
    const int sw = (l15 & 7) << 4;      // byte swizzle (16B granule)
    const int swu = (l15 & 7) << 3;     // same swizzle in u16 units
    const int m0 = w * 16;              // feature tile base (P1-P3)
    const int wq = w & 3;
    const int mq = wq * 16;             // dim tile base (P4 / enc / v-init)
    const bool isQ = (w >= 4);
    const int NS = *nsp;
    const float dtv = 1.0f / (float)NS; // T_SPAN = (0,1)
    const int TS = (NS + 1) * 128;
    const int b0 = blockIdx.x * ROWS;

    // Newton tile assignment: wave -> output tiles (rt, ct0), (rt, ct0+1)
    const int rt = w & 3, ct0 = (w >> 2) * 2;

    // ---- M = L L^T + 0.01 I via hi/lo MFMA; store transposed+swizzled in bufC ----
    {
        s16x8 Ah[2], Al[2];
        #pragma unroll
        for (int kt = 0; kt < 2; ++kt)
            ldfrag_hl(L + (size_t)(16*rt + l15)*DIM + kt*32 + 8*l4, Ah[kt], Al[kt]);
        #pragma unroll
        for (int ct = 0; ct < 2; ++ct){
            const int n = 16*(ct0+ct) + l15;
            f32x4 acc = {0.f,0.f,0.f,0.f};
            #pragma unroll
            for (int kt = 0; kt < 2; ++kt){
                s16x8 Bh, Bl;
                ldfrag_hl(L + (size_t)n*DIM + kt*32 + 8*l4, Bh, Bl);
                acc = mfma16(Ah[kt], Bh, acc);
                acc = mfma16(Ah[kt], Bl, acc);
                acc = mfma16(Al[kt], Bh, acc);
            }
            #pragma unroll
            for (int r = 0; r < 4; ++r)
                if (16*rt + 4*l4 + r == n) acc[r] += 0.01f;
            wr_hl(bufC, n*128 + ((32*rt + 8*l4) ^ sw), acc);
        }
    }
    barrier_lds();

    // ---- Gershgorin row sums of |M| (hi part suffices) ----
    {
        const int r = tid >> 3, c8 = (tid & 7) * 8;
        const unsigned short* mh = (const unsigned short*)bufC;
        s16x8 mv = *(const s16x8*)&mh[r*64 + (c8 ^ ((r&7)<<3))];
        float s = 0.f;
        #pragma unroll
        for (int j = 0; j < 8; ++j) s += fabsf(bf2f((unsigned short)mv[j]));
        fscr[tid] = s;
    }
    barrier_lds();
    if (tid < 64){
        float s = 0.f;
        #pragma unroll
        for (int j = 0; j < 8; ++j) s += fscr[tid*8 + j];
        fscr[512 + tid] = s;
    }
    barrier_lds();

    // ---- c, X0 = c I, M A-frags into registers ----
    s16x8 Mh[2], Ml[2];
    {
        float mrs = 0.f;
        for (int i = 0; i < 64; ++i) mrs = fmaxf(mrs, fscr[512 + i]);
        const float cN = 0.995f / mrs;
        const int r = tid >> 3, c8 = (tid & 7) * 8;
        union { s16x8 s; unsigned short us[8]; } Xh, Xl;
        #pragma unroll
        for (int j = 0; j < 8; ++j){ Xh.us[j] = 0; Xl.us[j] = 0; }
        const int d = r - c8;
        if (d >= 0 && d < 8){
            unsigned short h = f2bf(cN);
            Xh.us[d] = h;
            Xl.us[d] = f2bf(cN - bf2f(h));
        }
        const int idx = r*64 + (c8 ^ ((r&7)<<3));
        *(s16x8*)((unsigned short*)bufA + idx) = Xh.s;
        *(s16x8*)((unsigned short*)(bufA + 8192) + idx) = Xl.s;
        #pragma unroll
        for (int kt = 0; kt < 2; ++kt){
            const int ao = (16*rt + l15)*128 + ((kt*64 + 16*l4) ^ sw);
            Mh[kt] = *(const s16x8*)(bufC + ao);
            Ml[kt] = *(const s16x8*)(bufC + 8192 + ao);
        }
    }
    barrier_lds();

    // ---- Newton-Schulz x12 (stored transposed: SX = X^T, SY = Y^T) ----
    {
        char* pX = bufA; char* pY = bufB; char* pS = bufC;
        for (int it = 0; it < 12; ++it){
            // m1: Y = M.X  (B[k][n] = SX[n][k]); write SY[n][m]
            #pragma unroll
            for (int ct = 0; ct < 2; ++ct){
                const int n = 16*(ct0+ct) + l15;
                f32x4 acc = {0.f,0.f,0.f,0.f};
                #pragma unroll
                for (int kt = 0; kt < 2; ++kt){
                    const int bo = n*128 + ((kt*64 + 16*l4) ^ sw);
                    s16x8 bh = *(const s16x8*)(pX + bo);
                    s16x8 bl = *(const s16x8*)(pX + 8192 + bo);
                    acc = mfma16(Mh[kt], bh, acc);
                    acc = mfma16(Mh[kt], bl, acc);
                    acc = mfma16(Ml[kt], bh, acc);
                }
                wr_hl(pY, n*128 + ((32*rt + 8*l4) ^ sw), acc);
            }
            barrier_lds();
            // m2: X' = 2X - Y^T.X  (A = SY rows, B[k][n] = SX[n][k]); write SX'[n][m]
            #pragma unroll
            for (int ct = 0; ct < 2; ++ct){
                const int n = 16*(ct0+ct) + l15;
                f32x4 acc = {0.f,0.f,0.f,0.f};
                #pragma unroll
                for (int kt = 0; kt < 2; ++kt){
                    const int ao = (16*rt + l15)*128 + ((kt*64 + 16*l4) ^ sw);
                    s16x8 ah = *(const s16x8*)(pY + ao);
                    s16x8 al = *(const s16x8*)(pY + 8192 + ao);
                    const int bo = n*128 + ((kt*64 + 16*l4) ^ sw);
                    s16x8 bh = *(const s16x8*)(pX + bo);
                    s16x8 bl = *(const s16x8*)(pX + 8192 + bo);
                    acc = mfma16(ah, bh, acc);
                    acc = mfma16(ah, bl, acc);
                    acc = mfma16(al, bh, acc);
                }
                const int xo = n*128 + ((32*rt + 8*l4) ^ sw);
                u32x2 H = *(const u32x2*)(pX + xo);
                u32x2 Lo = *(const u32x2*)(pX + 8192 + xo);
                f32x4 nx;
                #pragma unroll
                for (int r = 0; r < 4; ++r){
                    unsigned hu = (r < 2) ? H[0] : H[1];
                    unsigned lu = (r < 2) ? Lo[0] : Lo[1];
                    unsigned short hh = (unsigned short)((r & 1) ? (hu >> 16) : (hu & 0xffff));
                    unsigned short ll = (unsigned short)((r & 1) ? (lu >> 16) : (lu & 0xffff));
                    float xv = bf2f(hh) + bf2f(ll);
                    nx[r] = 2.0f * xv - acc[r];
                }
                wr_hl(pS, xo, nx);
            }
            barrier_lds();
            char* t = pX; pX = pS; pS = pY; pY = t;   // 12 iters -> X back in bufA
        }
    }

    // ---- Minv (= X, transposed ~ symmetric) -> smh/sml (raw copy keeps swizzle) ----
    for (int i = tid; i < 1024; i += TMAIN)
        *(f32x4*)(shm + 32768 + 16*i) = *(const f32x4*)(shm + 16*i);
    barrier_lds();

    // ---- W1MT = Minv @ W1^T via MFMA (A = Minv hi/lo swizzled, B = W1 rows) ----
    {
        const int h0 = w * 16;
        #pragma unroll
        for (int d0 = 0; d0 < 64; d0 += 16){
            f32x4 acc = {0.f,0.f,0.f,0.f};
            #pragma unroll
            for (int kt = 0; kt < 2; ++kt){
                s16x8 fB = ldfrag_f32(W1 + (size_t)(h0+l15)*DIM + kt*32 + 8*l4);
                const int ui = (d0+l15)*DIM + ((kt*32 + 8*l4) ^ swu);
                s16x8 aH = *(const s16x8*)&smh[ui];
                s16x8 aL = *(const s16x8*)&sml[ui];
                acc = mfma16(aH, fB, acc);
                acc = mfma16(aL, fB, acc);
            }
            #pragma unroll
            for (int r = 0; r < 4; ++r)
                w1mt[(size_t)(d0 + 4*l4 + r)*HID + h0 + l15] = f2bf(acc[r]);
        }
    }
    barrier_lds();

    // ---- persistent weight A-fragments, straight from global f32 ----
    s16x8 fW1[2], fW2[4], fW2T[4], fP4[4];
    #pragma unroll
    for (int kt = 0; kt < 2; ++kt)
        fW1[kt] = ldfrag_f32(W1 + (size_t)(m0+l15)*DIM + kt*32 + 8*l4);
    #pragma unroll
    for (int kt = 0; kt < 4; ++kt){
        fW2[kt]  = ldfrag_f32(W2 + (size_t)(m0+l15)*HID + kt*32 + 8*l4);
        fW2T[kt] = ld_tr(W2 + (size_t)(kt*32 + 8*l4)*HID + m0 + l15, HID);
    }
    if (isQ){
        #pragma unroll
        for (int kt = 0; kt < 4; ++kt)
            fP4[kt] = *(const s16x8*)&w1mt[(mq+l15)*HID + kt*32 + 8*l4];
    } else {
        #pragma unroll
        for (int kt = 0; kt < 4; ++kt)
            fP4[kt] = ld_tr(W1 + (size_t)(kt*32 + 8*l4)*DIM + mq + l15, DIM);
    }

    const f32x4 bb1 = *(const f32x4*)&b1[m0 + 4*l4];
    const f32x4 bb2 = *(const f32x4*)&b2[m0 + 4*l4];
    const f32x4 bw3 = *(const f32x4*)&w3[m0 + 4*l4];

    // ---- encoder: waves4-7 -> q0, waves0-3 -> p0 (masters in registers) ----
    f32x4 master;
    {
        const float* zr = z + (size_t)(b0 + l15) * DIM;
        s16x8 bz0 = ldfrag_f32(zr + 8*l4);
        s16x8 bz1 = ldfrag_f32(zr + 32 + 8*l4);
        const float* eW = isQ ? qW : pW;
        const float* eb = isQ ? qb : pb;
        const float* wr = eW + (size_t)(mq + l15) * DIM;
        s16x8 fE0 = ldfrag_f32(wr + 8*l4);
        s16x8 fE1 = ldfrag_f32(wr + 32 + 8*l4);
        f32x4 acc = {0.f,0.f,0.f,0.f};
        acc = mfma16(fE0, bz0, acc);
        acc = mfma16(fE1, bz1, acc);
        f32x4 be = *(const f32x4*)&eb[mq + 4*l4];
        master = acc + be;
        if (isQ){
            u32x2 pr; pr[0] = pk2(master[0],master[1]); pr[1] = pk2(master[2],master[3]);
            *(u32x2*)(sQb_ + l15*128 + ((32*wq + 8*l4) ^ sw)) = pr;
        }
        const int ofs = isQ ? (mq + 4*l4) : (64 + mq + 4*l4);
        *(f32x4*)(out + (size_t)(b0 + l15) * TS + ofs) = master;
    }
    barrier_lds();

    f32x4 vm = {0.f,0.f,0.f,0.f};
    f32x4 pend = {0.f,0.f,0.f,0.f};

    for (int t = 0; t <= NS; ++t){
        // ---- P1: deferred traj stores, then h1 = q@W1^T + b1 ----
        {
            if (t >= 1){
                if (isQ)
                    *(f32x4*)(out + (size_t)(b0+l15)*TS + (size_t)t*128 + mq + 4*l4) = pend;
                else if (t >= 2)
                    *(f32x4*)(out + (size_t)(b0+l15)*TS + (size_t)(t-1)*128 + 64 + mq + 4*l4) = pend;
            }
            s16x8 bq0 = *(const s16x8*)(sQb_ + l15*128 + ((16*l4) ^ sw));
            s16x8 bq1 = *(const s16x8*)(sQb_ + l15*128 + ((64 + 16*l4) ^ sw));
            f32x4 a0 = {0.f,0.f,0.f,0.f}, a1v = {0.f,0.f,0.f,0.f};
            a0 = mfma16(fW1[0], bq0, a0);
            a1v = mfma16(fW1[1], bq1, a1v);
            f32x4 si, dv;
            #pragma unroll
            for (int r = 0; r < 4; ++r){
                float h = a0[r] + a1v[r] + bb1[r];
                float sg = 1.0f / (1.0f + __expf(-h));
                float s = h * sg;
                si[r] = s;
                dv[r] = sg + s * (1.0f - sg);
            }
            u32x2 pr; pr[0] = pk2(si[0],si[1]); pr[1] = pk2(si[2],si[3]);
            *(u32x2*)(sA1_ + l15*256 + ((2*m0 + 8*l4) ^ sw)) = pr;
            *(f32x4*)(sD1_ + l15*512 + ((4*m0 + 16*l4) ^ sw)) = dv;
        }
        barrier_lds();
        // ---- P2: h2 = a1@W2^T + b2 ; g2 = w3 * silu'(h2) ----
        {
            f32x4 a0 = {0.f,0.f,0.f,0.f}, a1v = {0.f,0.f,0.f,0.f};
            #pragma unroll
            for (int kt = 0; kt < 2; ++kt){
                s16x8 ba0 = *(const s16x8*)(sA1_ + l15*256 + ((64*(2*kt) + 16*l4) ^ sw));
                s16x8 ba1 = *(const s16x8*)(sA1_ + l15*256 + ((64*(2*kt+1) + 16*l4) ^ sw));
                a0 = mfma16(fW2[2*kt], ba0, a0);
                a1v = mfma16(fW2[2*kt+1], ba1, a1v);
            }
            f32x4 g2;
            #pragma unroll
            for (int r = 0; r < 4; ++r){
                float h = a0[r] + a1v[r] + bb2[r];
                float sg = 1.0f / (1.0f + __expf(-h));
                g2[r] = bw3[r] * (sg * (1.0f + h * (1.0f - sg)));
            }
            u32x2 pr; pr[0] = pk2(g2[0],g2[1]); pr[1] = pk2(g2[2],g2[3]);
            *(u32x2*)(sG2_ + l15*256 + ((2*m0 + 8*l4) ^ sw)) = pr;
        }
        barrier_lds();
        // ---- P3: g1 = (g2 @ W2) * d1 ----
        {
            f32x4 a0 = {0.f,0.f,0.f,0.f}, a1v = {0.f,0.f,0.f,0.f};
            #pragma unroll
            for (int kt = 0; kt < 2; ++kt){
                s16x8 bg0 = *(const s16x8*)(sG2_ + l15*256 + ((64*(2*kt) + 16*l4) ^ sw));
                s16x8 bg1 = *(const s16x8*)(sG2_ + l15*256 + ((64*(2*kt+1) + 16*l4) ^ sw));
                a0 = mfma16(fW2T[2*kt], bg0, a0);
                a1v = mfma16(fW2T[2*kt+1], bg1, a1v);
            }
            f32x4 dv = *(const f32x4*)(sD1_ + l15*512 + ((4*m0 + 16*l4) ^ sw));
            f32x4 g1;
            #pragma unroll
            for (int r = 0; r < 4; ++r) g1[r] = (a0[r] + a1v[r]) * dv[r];
            u32x2 pr; pr[0] = pk2(g1[0],g1[1]); pr[1] = pk2(g1[2],g1[3]);
            *(u32x2*)(sG1_ + l15*256 + ((2*m0 + 8*l4) ^ sw)) = pr;
        }
        barrier_lds();
        // ---- P4: w<4: grad=g1@W1 -> p; w>=4: wv=g1@W1MT -> v,q ----
        if (!isQ){
            f32x4 a0 = {0.f,0.f,0.f,0.f}, a1v = {0.f,0.f,0.f,0.f};
            #pragma unroll
            for (int kt = 0; kt < 2; ++kt){
                s16x8 bg0 = *(const s16x8*)(sG1_ + l15*256 + ((64*(2*kt) + 16*l4) ^ sw));
                s16x8 bg1 = *(const s16x8*)(sG1_ + l15*256 + ((64*(2*kt+1) + 16*l4) ^ sw));
                a0 = mfma16(fP4[2*kt], bg0, a0);
                a1v = mfma16(fP4[2*kt+1], bg1, a1v);
            }
            if (t == 0){
                #pragma unroll
                for (int r = 0; r < 4; ++r) master[r] -= 0.5f * dtv * (a0[r] + a1v[r]);
                u32x2 pr; pr[0] = pk2(master[0],master[1]); pr[1] = pk2(master[2],master[3]);
                *(u32x2*)(sPb_ + l15*128 + ((32*wq + 8*l4) ^ sw)) = pr;
            } else {
                #pragma unroll
                for (int r = 0; r < 4; ++r){
                    float g = a0[r] + a1v[r];
                    pend[r] = master[r] - 0.5f * dtv * g;   // p(t)
                    master[r] -= dtv * g;                    // p_half(t+1/2)
                }
            }
        } else if (t >= 1){
            f32x4 a0 = {0.f,0.f,0.f,0.f}, a1v = {0.f,0.f,0.f,0.f};
            #pragma unroll
            for (int kt = 0; kt < 2; ++kt){
                s16x8 bg0 = *(const s16x8*)(sG1_ + l15*256 + ((64*(2*kt) + 16*l4) ^ sw));
                s16x8 bg1 = *(const s16x8*)(sG1_ + l15*256 + ((64*(2*kt+1) + 16*l4) ^ sw));
                a0 = mfma16(fP4[2*kt], bg0, a0);
                a1v = mfma16(fP4[2*kt+1], bg1, a1v);
            }
            #pragma unroll
            for (int r = 0; r < 4; ++r){
                vm[r] -= dtv * (a0[r] + a1v[r]);   // v(t+1/2)
                master[r] += dtv * vm[r];          // q(t+1)
            }
            u32x2 pr; pr[0] = pk2(master[0],master[1]); pr[1] = pk2(master[2],master[3]);
            *(u32x2*)(sQb_ + l15*128 + ((32*wq + 8*l4) ^ sw)) = pr;
            pend = master;
        }
        barrier_lds();
        // ---- one-time v init after the first half-kick ----
        if (t == 0){
            if (isQ){
                s16x8 fMhi[2], fMlo[2];
                #pragma unroll
                for (int kt = 0; kt < 2; ++kt){
                    const int ui = (mq+l15)*DIM + ((kt*32 + 8*l4) ^ swu);
                    fMhi[kt] = *(const s16x8*)&smh[ui];
                    fMlo[kt] = *(const s16x8*)&sml[ui];
                }
                s16x8 bp0 = *(const s16x8*)(sPb_ + l15*128 + ((16*l4) ^ sw));
                s16x8 bp1 = *(const s16x8*)(sPb_ + l15*128 + ((64 + 16*l4) ^ sw));
                f32x4 aH = {0.f,0.f,0.f,0.f}, aL = {0.f,0.f,0.f,0.f};
                aH = mfma16(fMhi[0], bp0, aH);
                aH = mfma16(fMhi[1], bp1, aH);
                aL = mfma16(fMlo[0], bp0, aL);
                aL = mfma16(fMlo[1], bp1, aL);
                #pragma unroll
                for (int r = 0; r < 4; ++r){
                    vm[r] = aH[r] + aL[r];         // v(1/2)
                    master[r] += dtv * vm[r];      // q(1)
                }
                u32x2 pr; pr[0] = pk2(master[0],master[1]); pr[1] = pk2(master[2],master[3]);
                *(u32x2*)(sQb_ + l15*128 + ((32*wq + 8*l4) ^ sw)) = pr;
                pend = master;
            }
            barrier_lds();
        }
    }
    // flush last p-traj
    if (!isQ)
        *(f32x4*)(out + (size_t)(b0+l15)*TS + (size_t)NS*128 + 64 + mq + 4*l4) = pend;
}

extern "C" void kernel_launch(void* const* d_in, const int* in_sizes, int n_in,
                              void* d_out, int out_size, void* d_ws, size_t ws_size,
                              hipStream_t stream)
{
    const float* z  = (const float*)d_in[0];
    const float* L  = (const float*)d_in[1];
    const float* W1 = (const float*)d_in[2];
    const float* b1 = (const float*)d_in[3];
    const float* W2 = (const float*)d_in[4];
    const float* b2 = (const float*)d_in[5];
    const float* w3 = (const float*)d_in[6];
    // d_in[7] = Vb3: constant, vanishes in gradV
    const float* qW = (const float*)d_in[8];
    const float* qb = (const float*)d_in[9];
    const float* pW = (const float*)d_in[10];
    const float* pb = (const float*)d_in[11];
    const int* nsp  = (const int*)d_in[12];
    float* out = (float*)d_out;
    (void)d_ws; (void)ws_size;
    const int B = in_sizes[0] / DIM;

    k_main<<<B/ROWS, TMAIN, 0, stream>>>(z, L, W1, b1, W2, b2, w3, qW, qb, pW, pb, nsp, out);
}

// Round 9
// 151.619 us; speedup vs baseline: 1.6470x; 1.0003x over previous
//
#include <hip/hip_runtime.h>
#include <hip/hip_bf16.h>
#include <cstdint>
#include <cstddef>

#define HID 128
#define DIM 64
#define ROWS 16
#define TMAIN 512

typedef float f32x4 __attribute__((ext_vector_type(4)));
typedef short s16x8 __attribute__((ext_vector_type(8)));
typedef unsigned int u32x2 __attribute__((ext_vector_type(2)));

__device__ __forceinline__ unsigned short f2bf(float x){
    union { float f; unsigned int u; } v; v.f = x;
    unsigned int r = v.u + 0x7FFFu + ((v.u >> 16) & 1u);
    return (unsigned short)(r >> 16);
}
__device__ __forceinline__ float bf2f(unsigned short b){
    union { unsigned int u; float f; } v; v.u = ((unsigned int)b) << 16;
    return v.f;
}
__device__ __forceinline__ unsigned pk2(float a, float b){
    union { __hip_bfloat162 h; unsigned u; } cv;
    cv.h = __float22bfloat162_rn(make_float2(a, b));
    return cv.u;
}
__device__ __forceinline__ s16x8 mk8(unsigned a, unsigned b, unsigned c, unsigned d){
    union { s16x8 s; unsigned u[4]; } t; t.u[0]=a; t.u[1]=b; t.u[2]=c; t.u[3]=d; return t.s;
}
__device__ __forceinline__ s16x8 ldfrag_f32(const float* base){
    f32x4 a = *(const f32x4*)base;
    f32x4 b = *(const f32x4*)(base + 4);
    return mk8(pk2(a[0],a[1]), pk2(a[2],a[3]), pk2(b[0],b[1]), pk2(b[2],b[3]));
}
__device__ __forceinline__ void ldfrag_hl(const float* base, s16x8& hi, s16x8& lo){
    f32x4 a = *(const f32x4*)base;
    f32x4 b = *(const f32x4*)(base + 4);
    float x[8] = {a[0],a[1],a[2],a[3],b[0],b[1],b[2],b[3]};
    union { s16x8 s; unsigned short us[8]; } H, L;
    #pragma unroll
    for (int j = 0; j < 8; ++j){
        unsigned short h = f2bf(x[j]);
        H.us[j] = h;
        L.us[j] = f2bf(x[j] - bf2f(h));
    }
    hi = H.s; lo = L.s;
}
__device__ __forceinline__ s16x8 ld_tr(const float* p, int stride){
    unsigned u[4];
    #pragma unroll
    for (int j = 0; j < 4; ++j){
        float a = p[(2*j)*stride];
        float b = p[(2*j+1)*stride];
        u[j] = pk2(a, b);
    }
    return mk8(u[0], u[1], u[2], u[3]);
}
__device__ __forceinline__ f32x4 mfma16(s16x8 a, s16x8 b, f32x4 c){
    return __builtin_amdgcn_mfma_f32_16x16x32_bf16(a, b, c, 0, 0, 0);
}
__device__ __forceinline__ void wr_hl(char* buf, int off, f32x4 v){
    unsigned short h[4], l[4];
    #pragma unroll
    for (int r = 0; r < 4; ++r){
        h[r] = f2bf(v[r]);
        l[r] = f2bf(v[r] - bf2f(h[r]));
    }
    u32x2 H, L;
    H[0] = (unsigned)h[0] | ((unsigned)h[1] << 16);
    H[1] = (unsigned)h[2] | ((unsigned)h[3] << 16);
    L[0] = (unsigned)l[0] | ((unsigned)l[1] << 16);
    L[1] = (unsigned)l[2] | ((unsigned)l[3] << 16);
    *(u32x2*)(buf + off) = H;
    *(u32x2*)(buf + 8192 + off) = L;
}
// LDS-only barrier: skips the vmcnt(0) drain __syncthreads would force.
__device__ __forceinline__ void barrier_lds(){
    asm volatile("s_waitcnt lgkmcnt(0)" ::: "memory");
    __builtin_amdgcn_s_barrier();
    asm volatile("" ::: "memory");
}

// ---------------- single fused kernel ----------------
// Prep (8 waves, redundant per block): M = LL^T+0.01I via hi/lo MFMA; Gershgorin c
// (shuffle-max); Newton-Schulz x12 (transposed hi/lo bf16, 2 barriers/iter);
// W1MT = Minv@W1^T via MFMA (hoisted B-frags).
// Step loop (waves 0-3 compute, waves 4-7 barrier-only): each compute wave owns
// 2 feature tiles (P1-P3; B-frags read ONCE, reused) and one dim tile with BOTH
// P4 matmuls (grad=g1@W1T for p, wv=g1@W1MT for q/v) -> LDS reads/step 160->~100.
__global__ __launch_bounds__(TMAIN) void k_main(
    const float* __restrict__ z, const float* __restrict__ L,
    const float* __restrict__ W1, const float* __restrict__ b1,
    const float* __restrict__ W2, const float* __restrict__ b2,
    const float* __restrict__ w3, const float* __restrict__ qW,
    const float* __restrict__ qb, const float* __restrict__ pW,
    const float* __restrict__ pb, const int* __restrict__ nsp,
    float* __restrict__ out)
{
    __shared__ __align__(16) char shm[65536];
    char* const sQb_ = shm;             // bf16 [16][64]   2048
    char* const sPb_ = shm + 2048;      // bf16 [16][64]   2048
    char* const sA1_ = shm + 4096;      // bf16 [16][128]  4096
    char* const sG2_ = shm + 8192;      // bf16 [16][128]  4096
    char* const sG1_ = shm + 12288;     // bf16 [16][128]  4096
    char* const sD1_ = shm + 16384;     // f32  [16][128]  8192 (end 24576)
    char* const bufA = shm;             // Newton scratch (prep only)
    char* const bufB = shm + 16384;
    char* const bufC = shm + 32768;     // M -> rotation -> Minv hi/lo
    unsigned short* const smh = (unsigned short*)(shm + 32768);
    unsigned short* const sml = (unsigned short*)(shm + 40960);
    unsigned short* const w1mt = (unsigned short*)(shm + 49152);
    float* const fscr = (float*)(shm + 49152);   // rowsum scratch (pre-W1MT)

    const int tid = threadIdx.x;
    const int w = tid >> 6, lane = tid & 63;
    const int l15 = lane & 15, l4 = lane >> 4;
    const int sw = (l15 & 7) << 4;      // byte swizzle (16B granule)
    const int swu = (l15 & 7) << 3;     // same swizzle in u16 units
    const bool cw = (w < 4);            // step-loop compute wave
    const int mq = (w & 3) * 16;        // dim tile base
    const int NS = *nsp;
    const float dtv = 1.0f / (float)NS; // T_SPAN = (0,1)
    const int TS = (NS + 1) * 128;
    const int b0 = blockIdx.x * ROWS;

    // Newton tile assignment (8-wave prep): wave -> tiles (rt, ct0), (rt, ct0+1)
    const int rt = w & 3, ct0 = (w >> 2) * 2;

    // ---- M = L L^T + 0.01 I via hi/lo MFMA; store transposed+swizzled in bufC ----
    {
        s16x8 Ah[2], Al[2];
        #pragma unroll
        for (int kt = 0; kt < 2; ++kt)
            ldfrag_hl(L + (size_t)(16*rt + l15)*DIM + kt*32 + 8*l4, Ah[kt], Al[kt]);
        #pragma unroll
        for (int ct = 0; ct < 2; ++ct){
            const int n = 16*(ct0+ct) + l15;
            f32x4 acc = {0.f,0.f,0.f,0.f};
            #pragma unroll
            for (int kt = 0; kt < 2; ++kt){
                s16x8 Bh, Bl;
                ldfrag_hl(L + (size_t)n*DIM + kt*32 + 8*l4, Bh, Bl);
                acc = mfma16(Ah[kt], Bh, acc);
                acc = mfma16(Ah[kt], Bl, acc);
                acc = mfma16(Al[kt], Bh, acc);
            }
            #pragma unroll
            for (int r = 0; r < 4; ++r)
                if (16*rt + 4*l4 + r == n) acc[r] += 0.01f;
            wr_hl(bufC, n*128 + ((32*rt + 8*l4) ^ sw), acc);
        }
    }
    barrier_lds();

    // ---- Gershgorin row sums of |M| ----
    {
        const int r = tid >> 3, c8 = (tid & 7) * 8;
        const unsigned short* mh = (const unsigned short*)bufC;
        s16x8 mv = *(const s16x8*)&mh[r*64 + (c8 ^ ((r&7)<<3))];
        float s = 0.f;
        #pragma unroll
        for (int j = 0; j < 8; ++j) s += fabsf(bf2f((unsigned short)mv[j]));
        fscr[tid] = s;
    }
    barrier_lds();
    if (tid < 64){
        float s = 0.f;
        #pragma unroll
        for (int j = 0; j < 8; ++j) s += fscr[tid*8 + j];
        fscr[512 + tid] = s;
    }
    barrier_lds();

    // ---- c via shuffle-max (no serial chain), X0 = c I, M A-frags to registers ----
    s16x8 Mh[2], Ml[2];
    {
        float mrs = fscr[512 + lane];           // lane l holds row-sum l
        #pragma unroll
        for (int off = 1; off < 64; off <<= 1)
            mrs = fmaxf(mrs, __shfl_xor(mrs, off));
        const float cN = 0.995f / mrs;
        const int r = tid >> 3, c8 = (tid & 7) * 8;
        union { s16x8 s; unsigned short us[8]; } Xh, Xl;
        #pragma unroll
        for (int j = 0; j < 8; ++j){ Xh.us[j] = 0; Xl.us[j] = 0; }
        const int d = r - c8;
        if (d >= 0 && d < 8){
            unsigned short h = f2bf(cN);
            Xh.us[d] = h;
            Xl.us[d] = f2bf(cN - bf2f(h));
        }
        const int idx = r*64 + (c8 ^ ((r&7)<<3));
        *(s16x8*)((unsigned short*)bufA + idx) = Xh.s;
        *(s16x8*)((unsigned short*)(bufA + 8192) + idx) = Xl.s;
        #pragma unroll
        for (int kt = 0; kt < 2; ++kt){
            const int ao = (16*rt + l15)*128 + ((kt*64 + 16*l4) ^ sw);
            Mh[kt] = *(const s16x8*)(bufC + ao);
            Ml[kt] = *(const s16x8*)(bufC + 8192 + ao);
        }
    }
    barrier_lds();

    // ---- Newton-Schulz x12 (stored transposed: SX = X^T, SY = Y^T) ----
    {
        char* pX = bufA; char* pY = bufB; char* pS = bufC;
        for (int it = 0; it < 12; ++it){
            #pragma unroll
            for (int ct = 0; ct < 2; ++ct){
                const int n = 16*(ct0+ct) + l15;
                f32x4 acc = {0.f,0.f,0.f,0.f};
                #pragma unroll
                for (int kt = 0; kt < 2; ++kt){
                    const int bo = n*128 + ((kt*64 + 16*l4) ^ sw);
                    s16x8 bh = *(const s16x8*)(pX + bo);
                    s16x8 bl = *(const s16x8*)(pX + 8192 + bo);
                    acc = mfma16(Mh[kt], bh, acc);
                    acc = mfma16(Mh[kt], bl, acc);
                    acc = mfma16(Ml[kt], bh, acc);
                }
                wr_hl(pY, n*128 + ((32*rt + 8*l4) ^ sw), acc);
            }
            barrier_lds();
            #pragma unroll
            for (int ct = 0; ct < 2; ++ct){
                const int n = 16*(ct0+ct) + l15;
                f32x4 acc = {0.f,0.f,0.f,0.f};
                #pragma unroll
                for (int kt = 0; kt < 2; ++kt){
                    const int ao = (16*rt + l15)*128 + ((kt*64 + 16*l4) ^ sw);
                    s16x8 ah = *(const s16x8*)(pY + ao);
                    s16x8 al = *(const s16x8*)(pY + 8192 + ao);
                    const int bo = n*128 + ((kt*64 + 16*l4) ^ sw);
                    s16x8 bh = *(const s16x8*)(pX + bo);
                    s16x8 bl = *(const s16x8*)(pX + 8192 + bo);
                    acc = mfma16(ah, bh, acc);
                    acc = mfma16(ah, bl, acc);
                    acc = mfma16(al, bh, acc);
                }
                const int xo = n*128 + ((32*rt + 8*l4) ^ sw);
                u32x2 H = *(const u32x2*)(pX + xo);
                u32x2 Lo = *(const u32x2*)(pX + 8192 + xo);
                f32x4 nx;
                #pragma unroll
                for (int r = 0; r < 4; ++r){
                    unsigned hu = (r < 2) ? H[0] : H[1];
                    unsigned lu = (r < 2) ? Lo[0] : Lo[1];
                    unsigned short hh = (unsigned short)((r & 1) ? (hu >> 16) : (hu & 0xffff));
                    unsigned short ll = (unsigned short)((r & 1) ? (lu >> 16) : (lu & 0xffff));
                    float xv = bf2f(hh) + bf2f(ll);
                    nx[r] = 2.0f * xv - acc[r];
                }
                wr_hl(pS, xo, nx);
            }
            barrier_lds();
            char* t = pX; pX = pS; pS = pY; pY = t;   // 12 iters -> X back in bufA
        }
    }

    // ---- Minv -> smh/sml (raw copy keeps swizzle) ----
    for (int i = tid; i < 1024; i += TMAIN)
        *(f32x4*)(shm + 32768 + 16*i) = *(const f32x4*)(shm + 16*i);
    barrier_lds();

    // ---- W1MT = Minv @ W1^T via MFMA (hoisted B-frags) ----
    {
        const int h0 = w * 16;
        s16x8 fB0 = ldfrag_f32(W1 + (size_t)(h0+l15)*DIM + 8*l4);
        s16x8 fB1 = ldfrag_f32(W1 + (size_t)(h0+l15)*DIM + 32 + 8*l4);
        #pragma unroll
        for (int d0 = 0; d0 < 64; d0 += 16){
            f32x4 acc = {0.f,0.f,0.f,0.f};
            const int u0 = (d0+l15)*DIM + ((8*l4) ^ swu);
            const int u1 = (d0+l15)*DIM + ((32 + 8*l4) ^ swu);
            acc = mfma16(*(const s16x8*)&smh[u0], fB0, acc);
            acc = mfma16(*(const s16x8*)&sml[u0], fB0, acc);
            acc = mfma16(*(const s16x8*)&smh[u1], fB1, acc);
            acc = mfma16(*(const s16x8*)&sml[u1], fB1, acc);
            #pragma unroll
            for (int r = 0; r < 4; ++r)
                w1mt[(size_t)(d0 + 4*l4 + r)*HID + h0 + l15] = f2bf(acc[r]);
        }
    }
    barrier_lds();

    // ---- step-loop weights (compute waves only): 2 feature tiles + merged P4 ----
    s16x8 fW1[2][2], fW2[2][4], fW2T[2][4], fP4p[4], fP4q[4];
    f32x4 bb1[2], bb2[2], bw3[2];
    f32x4 master_q = {0.f,0.f,0.f,0.f}, master_p = {0.f,0.f,0.f,0.f};
    if (cw){
        #pragma unroll
        for (int tt = 0; tt < 2; ++tt){
            const int m0 = 32*w + 16*tt;
            #pragma unroll
            for (int kt = 0; kt < 2; ++kt)
                fW1[tt][kt] = ldfrag_f32(W1 + (size_t)(m0+l15)*DIM + kt*32 + 8*l4);
            #pragma unroll
            for (int kt = 0; kt < 4; ++kt){
                fW2[tt][kt]  = ldfrag_f32(W2 + (size_t)(m0+l15)*HID + kt*32 + 8*l4);
                fW2T[tt][kt] = ld_tr(W2 + (size_t)(kt*32 + 8*l4)*HID + m0 + l15, HID);
            }
            bb1[tt] = *(const f32x4*)&b1[m0 + 4*l4];
            bb2[tt] = *(const f32x4*)&b2[m0 + 4*l4];
            bw3[tt] = *(const f32x4*)&w3[m0 + 4*l4];
        }
        #pragma unroll
        for (int kt = 0; kt < 4; ++kt){
            fP4q[kt] = *(const s16x8*)&w1mt[(mq+l15)*HID + kt*32 + 8*l4];
            fP4p[kt] = ld_tr(W1 + (size_t)(kt*32 + 8*l4)*DIM + mq + l15, DIM);
        }
        // ---- encoder: q0 AND p0 for this wave's dim slice ----
        const float* zr = z + (size_t)(b0 + l15) * DIM;
        s16x8 bz0 = ldfrag_f32(zr + 8*l4);
        s16x8 bz1 = ldfrag_f32(zr + 32 + 8*l4);
        s16x8 fq0 = ldfrag_f32(qW + (size_t)(mq+l15)*DIM + 8*l4);
        s16x8 fq1 = ldfrag_f32(qW + (size_t)(mq+l15)*DIM + 32 + 8*l4);
        s16x8 fp0 = ldfrag_f32(pW + (size_t)(mq+l15)*DIM + 8*l4);
        s16x8 fp1 = ldfrag_f32(pW + (size_t)(mq+l15)*DIM + 32 + 8*l4);
        f32x4 aq = {0.f,0.f,0.f,0.f}, ap = {0.f,0.f,0.f,0.f};
        aq = mfma16(fq0, bz0, aq); aq = mfma16(fq1, bz1, aq);
        ap = mfma16(fp0, bz0, ap); ap = mfma16(fp1, bz1, ap);
        master_q = aq + *(const f32x4*)&qb[mq + 4*l4];
        master_p = ap + *(const f32x4*)&pb[mq + 4*l4];
        u32x2 pr; pr[0] = pk2(master_q[0],master_q[1]); pr[1] = pk2(master_q[2],master_q[3]);
        *(u32x2*)(sQb_ + l15*128 + ((32*(w&3) + 8*l4) ^ sw)) = pr;
        *(f32x4*)(out + (size_t)(b0 + l15) * TS + mq + 4*l4) = master_q;
        *(f32x4*)(out + (size_t)(b0 + l15) * TS + 64 + mq + 4*l4) = master_p;
    }
    barrier_lds();

    f32x4 vm = {0.f,0.f,0.f,0.f};
    f32x4 pend_q = {0.f,0.f,0.f,0.f}, pend_p = {0.f,0.f,0.f,0.f};

    for (int t = 0; t <= NS; ++t){
        // ---- P1: deferred traj stores, then h1 = q@W1^T + b1 (2 tiles) ----
        if (cw){
            if (t >= 1){
                *(f32x4*)(out + (size_t)(b0+l15)*TS + (size_t)t*128 + mq + 4*l4) = pend_q;
                if (t >= 2)
                    *(f32x4*)(out + (size_t)(b0+l15)*TS + (size_t)(t-1)*128 + 64 + mq + 4*l4) = pend_p;
            }
            s16x8 bq0 = *(const s16x8*)(sQb_ + l15*128 + ((16*l4) ^ sw));
            s16x8 bq1 = *(const s16x8*)(sQb_ + l15*128 + ((64 + 16*l4) ^ sw));
            #pragma unroll
            for (int tt = 0; tt < 2; ++tt){
                const int m0 = 32*w + 16*tt;
                f32x4 a0 = {0.f,0.f,0.f,0.f}, a1v = {0.f,0.f,0.f,0.f};
                a0 = mfma16(fW1[tt][0], bq0, a0);
                a1v = mfma16(fW1[tt][1], bq1, a1v);
                f32x4 si, dv;
                #pragma unroll
                for (int r = 0; r < 4; ++r){
                    float h = a0[r] + a1v[r] + bb1[tt][r];
                    float sg = 1.0f / (1.0f + __expf(-h));
                    float s = h * sg;
                    si[r] = s;
                    dv[r] = sg + s * (1.0f - sg);
                }
                u32x2 pr; pr[0] = pk2(si[0],si[1]); pr[1] = pk2(si[2],si[3]);
                *(u32x2*)(sA1_ + l15*256 + ((2*m0 + 8*l4) ^ sw)) = pr;
                *(f32x4*)(sD1_ + l15*512 + ((4*m0 + 16*l4) ^ sw)) = dv;
            }
        }
        barrier_lds();
        // ---- P2: h2 = a1@W2^T + b2 ; g2 = w3 * silu'(h2) (2 tiles, shared B) ----
        if (cw){
            s16x8 ba[4];
            #pragma unroll
            for (int kt = 0; kt < 4; ++kt)
                ba[kt] = *(const s16x8*)(sA1_ + l15*256 + ((64*kt + 16*l4) ^ sw));
            #pragma unroll
            for (int tt = 0; tt < 2; ++tt){
                const int m0 = 32*w + 16*tt;
                f32x4 a0 = {0.f,0.f,0.f,0.f}, a1v = {0.f,0.f,0.f,0.f};
                a0 = mfma16(fW2[tt][0], ba[0], a0);
                a1v = mfma16(fW2[tt][1], ba[1], a1v);
                a0 = mfma16(fW2[tt][2], ba[2], a0);
                a1v = mfma16(fW2[tt][3], ba[3], a1v);
                f32x4 g2;
                #pragma unroll
                for (int r = 0; r < 4; ++r){
                    float h = a0[r] + a1v[r] + bb2[tt][r];
                    float sg = 1.0f / (1.0f + __expf(-h));
                    g2[r] = bw3[tt][r] * (sg * (1.0f + h * (1.0f - sg)));
                }
                u32x2 pr; pr[0] = pk2(g2[0],g2[1]); pr[1] = pk2(g2[2],g2[3]);
                *(u32x2*)(sG2_ + l15*256 + ((2*m0 + 8*l4) ^ sw)) = pr;
            }
        }
        barrier_lds();
        // ---- P3: g1 = (g2 @ W2) * d1 (2 tiles, shared B) ----
        if (cw){
            s16x8 bg[4];
            #pragma unroll
            for (int kt = 0; kt < 4; ++kt)
                bg[kt] = *(const s16x8*)(sG2_ + l15*256 + ((64*kt + 16*l4) ^ sw));
            #pragma unroll
            for (int tt = 0; tt < 2; ++tt){
                const int m0 = 32*w + 16*tt;
                f32x4 a0 = {0.f,0.f,0.f,0.f}, a1v = {0.f,0.f,0.f,0.f};
                a0 = mfma16(fW2T[tt][0], bg[0], a0);
                a1v = mfma16(fW2T[tt][1], bg[1], a1v);
                a0 = mfma16(fW2T[tt][2], bg[2], a0);
                a1v = mfma16(fW2T[tt][3], bg[3], a1v);
                f32x4 dv = *(const f32x4*)(sD1_ + l15*512 + ((4*m0 + 16*l4) ^ sw));
                f32x4 g1;
                #pragma unroll
                for (int r = 0; r < 4; ++r) g1[r] = (a0[r] + a1v[r]) * dv[r];
                u32x2 pr; pr[0] = pk2(g1[0],g1[1]); pr[1] = pk2(g1[2],g1[3]);
                *(u32x2*)(sG1_ + l15*256 + ((2*m0 + 8*l4) ^ sw)) = pr;
            }
        }
        barrier_lds();
        // ---- P4 (merged): grad = g1@W1T -> p ; wv = g1@W1MT -> v,q ----
        if (cw){
            s16x8 bg[4];
            #pragma unroll
            for (int kt = 0; kt < 4; ++kt)
                bg[kt] = *(const s16x8*)(sG1_ + l15*256 + ((64*kt + 16*l4) ^ sw));
            f32x4 gp0 = {0.f,0.f,0.f,0.f}, gp1 = {0.f,0.f,0.f,0.f};
            f32x4 gq0 = {0.f,0.f,0.f,0.f}, gq1 = {0.f,0.f,0.f,0.f};
            gp0 = mfma16(fP4p[0], bg[0], gp0); gp1 = mfma16(fP4p[1], bg[1], gp1);
            gq0 = mfma16(fP4q[0], bg[0], gq0); gq1 = mfma16(fP4q[1], bg[1], gq1);
            gp0 = mfma16(fP4p[2], bg[2], gp0); gp1 = mfma16(fP4p[3], bg[3], gp1);
            gq0 = mfma16(fP4q[2], bg[2], gq0); gq1 = mfma16(fP4q[3], bg[3], gq1);
            if (t == 0){
                #pragma unroll
                for (int r = 0; r < 4; ++r) master_p[r] -= 0.5f * dtv * (gp0[r] + gp1[r]);
                u32x2 pr; pr[0] = pk2(master_p[0],master_p[1]); pr[1] = pk2(master_p[2],master_p[3]);
                *(u32x2*)(sPb_ + l15*128 + ((32*(w&3) + 8*l4) ^ sw)) = pr;
            } else {
                #pragma unroll
                for (int r = 0; r < 4; ++r){
                    float g = gp0[r] + gp1[r];
                    pend_p[r] = master_p[r] - 0.5f * dtv * g;   // p(t)
                    master_p[r] -= dtv * g;                      // p_half(t+1/2)
                    vm[r] -= dtv * (gq0[r] + gq1[r]);            // v(t+1/2)
                    master_q[r] += dtv * vm[r];                  // q(t+1)
                }
                u32x2 pr; pr[0] = pk2(master_q[0],master_q[1]); pr[1] = pk2(master_q[2],master_q[3]);
                *(u32x2*)(sQb_ + l15*128 + ((32*(w&3) + 8*l4) ^ sw)) = pr;
                pend_q = master_q;
            }
        }
        barrier_lds();
        // ---- one-time v init after the first half-kick ----
        if (t == 0){
            if (cw){
                s16x8 fMhi[2], fMlo[2];
                #pragma unroll
                for (int kt = 0; kt < 2; ++kt){
                    const int ui = (mq+l15)*DIM + ((kt*32 + 8*l4) ^ swu);
                    fMhi[kt] = *(const s16x8*)&smh[ui];
                    fMlo[kt] = *(const s16x8*)&sml[ui];
                }
                s16x8 bp0 = *(const s16x8*)(sPb_ + l15*128 + ((16*l4) ^ sw));
                s16x8 bp1 = *(const s16x8*)(sPb_ + l15*128 + ((64 + 16*l4) ^ sw));
                f32x4 aH = {0.f,0.f,0.f,0.f}, aL = {0.f,0.f,0.f,0.f};
                aH = mfma16(fMhi[0], bp0, aH);
                aH = mfma16(fMhi[1], bp1, aH);
                aL = mfma16(fMlo[0], bp0, aL);
                aL = mfma16(fMlo[1], bp1, aL);
                #pragma unroll
                for (int r = 0; r < 4; ++r){
                    vm[r] = aH[r] + aL[r];         // v(1/2)
                    master_q[r] += dtv * vm[r];    // q(1)
                }
                u32x2 pr; pr[0] = pk2(master_q[0],master_q[1]); pr[1] = pk2(master_q[2],master_q[3]);
                *(u32x2*)(sQb_ + l15*128 + ((32*(w&3) + 8*l4) ^ sw)) = pr;
                pend_q = master_q;
            }
            barrier_lds();
        }
    }
    // flush last p-traj
    if (cw)
        *(f32x4*)(out + (size_t)(b0+l15)*TS + (size_t)NS*128 + 64 + mq + 4*l4) = pend_p;
}

extern "C" void kernel_launch(void* const* d_in, const int* in_sizes, int n_in,
                              void* d_out, int out_size, void* d_ws, size_t ws_size,
                              hipStream_t stream)
{
    const float* z  = (const float*)d_in[0];
    const float* L  = (const float*)d_in[1];
    const float* W1 = (const float*)d_in[2];
    const float* b1 = (const float*)d_in[3];
    const float* W2 = (const float*)d_in[4];
    const float* b2 = (const float*)d_in[5];
    const float* w3 = (const float*)d_in[6];
    // d_in[7] = Vb3: constant, vanishes in gradV
    const float* qW = (const float*)d_in[8];
    const float* qb = (const float*)d_in[9];
    const float* pW = (const float*)d_in[10];
    const float* pb = (const float*)d_in[11];
    const int* nsp  = (const int*)d_in[12];
    float* out = (float*)d_out;
    (void)d_ws; (void)ws_size;
    const int B = in_sizes[0] / DIM;

    k_main<<<B/ROWS, TMAIN, 0, stream>>>(z, L, W1, b1, W2, b2, w3, qW, qb, pW, pb, nsp, out);
}

// Round 10
// 129.748 us; speedup vs baseline: 1.9246x; 1.1686x over previous
//
#include <hip/hip_runtime.h>
#include <hip/hip_bf16.h>
#include <cstdint>
#include <cstddef>

#define HID 128
#define DIM 64
#define ROWS 16
#define TMAIN 512

typedef float f32x4 __attribute__((ext_vector_type(4)));
typedef short s16x8 __attribute__((ext_vector_type(8)));
typedef unsigned int u32x2 __attribute__((ext_vector_type(2)));

__device__ __forceinline__ unsigned short f2bf(float x){
    union { float f; unsigned int u; } v; v.f = x;
    unsigned int r = v.u + 0x7FFFu + ((v.u >> 16) & 1u);
    return (unsigned short)(r >> 16);
}
__device__ __forceinline__ float bf2f(unsigned short b){
    union { unsigned int u; float f; } v; v.u = ((unsigned int)b) << 16;
    return v.f;
}
__device__ __forceinline__ unsigned pk2(float a, float b){
    union { __hip_bfloat162 h; unsigned u; } cv;
    cv.h = __float22bfloat162_rn(make_float2(a, b));
    return cv.u;
}
__device__ __forceinline__ s16x8 mk8(unsigned a, unsigned b, unsigned c, unsigned d){
    union { s16x8 s; unsigned u[4]; } t; t.u[0]=a; t.u[1]=b; t.u[2]=c; t.u[3]=d; return t.s;
}
__device__ __forceinline__ s16x8 ldfrag_f32(const float* base){
    f32x4 a = *(const f32x4*)base;
    f32x4 b = *(const f32x4*)(base + 4);
    return mk8(pk2(a[0],a[1]), pk2(a[2],a[3]), pk2(b[0],b[1]), pk2(b[2],b[3]));
}
__device__ __forceinline__ void ldfrag_hl(const float* base, s16x8& hi, s16x8& lo){
    f32x4 a = *(const f32x4*)base;
    f32x4 b = *(const f32x4*)(base + 4);
    float x[8] = {a[0],a[1],a[2],a[3],b[0],b[1],b[2],b[3]};
    union { s16x8 s; unsigned short us[8]; } H, L;
    #pragma unroll
    for (int j = 0; j < 8; ++j){
        unsigned short h = f2bf(x[j]);
        H.us[j] = h;
        L.us[j] = f2bf(x[j] - bf2f(h));
    }
    hi = H.s; lo = L.s;
}
__device__ __forceinline__ f32x4 mfma16(s16x8 a, s16x8 b, f32x4 c){
    return __builtin_amdgcn_mfma_f32_16x16x32_bf16(a, b, c, 0, 0, 0);
}
__device__ __forceinline__ void wr_hl(char* buf, int off, f32x4 v){
    unsigned short h[4], l[4];
    #pragma unroll
    for (int r = 0; r < 4; ++r){
        h[r] = f2bf(v[r]);
        l[r] = f2bf(v[r] - bf2f(h[r]));
    }
    u32x2 H, L;
    H[0] = (unsigned)h[0] | ((unsigned)h[1] << 16);
    H[1] = (unsigned)h[2] | ((unsigned)h[3] << 16);
    L[0] = (unsigned)l[0] | ((unsigned)l[1] << 16);
    L[1] = (unsigned)l[2] | ((unsigned)l[3] << 16);
    *(u32x2*)(buf + off) = H;
    *(u32x2*)(buf + 8192 + off) = L;
}
// LDS-only barrier: skips the vmcnt(0) drain __syncthreads would force.
__device__ __forceinline__ void barrier_lds(){
    asm volatile("s_waitcnt lgkmcnt(0)" ::: "memory");
    __builtin_amdgcn_s_barrier();
    asm volatile("" ::: "memory");
}

// workspace layout (bytes) — 81920 used
#define WS_W1MT 0          // bf16 [64][128]  (Minv @ W1^T)
#define WS_MHI  16384      // bf16 [64][64]   Minv hi (t=0 v-init)
#define WS_MLO  24576      // bf16 [64][64]   Minv lo
#define WS_W1T  32768      // bf16 [64][128]  W1^T
#define WS_W2T  49152      // bf16 [128][128] W2^T

// ---------------- kernel 1 (2 blocks): block0 = Newton-Schulz inverse + W1MT;
//                  block1 = transposed weight bf16 prep ----------------
__global__ __launch_bounds__(512) void k_prep(
    const float* __restrict__ L, const float* __restrict__ W1,
    const float* __restrict__ W2, char* __restrict__ ws)
{
    const int tid = threadIdx.x;
    if (blockIdx.x == 1){
        unsigned short* w1t = (unsigned short*)(ws + WS_W1T);
        unsigned short* w2t = (unsigned short*)(ws + WS_W2T);
        for (int i = tid; i < HID*DIM; i += 512){
            int h = i >> 6, d = i & 63;
            w1t[d*HID + h] = f2bf(W1[i]);
        }
        for (int i = tid; i < HID*HID; i += 512){
            int c2 = i >> 7, c1 = i & 127;
            w2t[c1*HID + c2] = f2bf(W2[i]);
        }
        return;
    }
    // ---- block 0: M = LL^T + 0.01I -> Newton-Schulz x12 -> Mhi/Mlo + W1MT ----
    __shared__ __align__(16) char nbuf[51712];
    char* const bufA = nbuf;            // X hi/lo (16KB: hi 8K, lo 8K)
    char* const bufB = nbuf + 16384;
    char* const bufC = nbuf + 32768;    // M hi/lo
    float* const fscr = (float*)(nbuf + 49152);

    const int w = tid >> 6, lane = tid & 63;
    const int l15 = lane & 15, l4 = lane >> 4;
    const int sw = (l15 & 7) << 4;      // byte swizzle, 16B granule
    const int rt = w & 3, ct0 = (w >> 2) * 2;

    // M = L L^T + 0.01 I via hi/lo MFMA; store transposed+swizzled in bufC
    {
        s16x8 Ah[2], Al[2];
        #pragma unroll
        for (int kt = 0; kt < 2; ++kt)
            ldfrag_hl(L + (size_t)(16*rt + l15)*DIM + kt*32 + 8*l4, Ah[kt], Al[kt]);
        #pragma unroll
        for (int ct = 0; ct < 2; ++ct){
            const int n = 16*(ct0+ct) + l15;
            f32x4 acc = {0.f,0.f,0.f,0.f};
            #pragma unroll
            for (int kt = 0; kt < 2; ++kt){
                s16x8 Bh, Bl;
                ldfrag_hl(L + (size_t)n*DIM + kt*32 + 8*l4, Bh, Bl);
                acc = mfma16(Ah[kt], Bh, acc);
                acc = mfma16(Ah[kt], Bl, acc);
                acc = mfma16(Al[kt], Bh, acc);
            }
            #pragma unroll
            for (int r = 0; r < 4; ++r)
                if (16*rt + 4*l4 + r == n) acc[r] += 0.01f;
            wr_hl(bufC, n*128 + ((32*rt + 8*l4) ^ sw), acc);
        }
    }
    barrier_lds();

    // Gershgorin row sums of |M|
    {
        const int r = tid >> 3, c8 = (tid & 7) * 8;
        const unsigned short* mh = (const unsigned short*)bufC;
        s16x8 mv = *(const s16x8*)&mh[r*64 + (c8 ^ ((r&7)<<3))];
        float s = 0.f;
        #pragma unroll
        for (int j = 0; j < 8; ++j) s += fabsf(bf2f((unsigned short)mv[j]));
        fscr[tid] = s;
    }
    barrier_lds();
    if (tid < 64){
        float s = 0.f;
        #pragma unroll
        for (int j = 0; j < 8; ++j) s += fscr[tid*8 + j];
        fscr[512 + tid] = s;
    }
    barrier_lds();

    // c via shuffle-max, X0 = c I, M A-frags to registers
    s16x8 Mh[2], Ml[2];
    {
        float mrs = fscr[512 + lane];
        #pragma unroll
        for (int off = 1; off < 64; off <<= 1)
            mrs = fmaxf(mrs, __shfl_xor(mrs, off));
        const float cN = 0.995f / mrs;
        const int r = tid >> 3, c8 = (tid & 7) * 8;
        union { s16x8 s; unsigned short us[8]; } Xh, Xl;
        #pragma unroll
        for (int j = 0; j < 8; ++j){ Xh.us[j] = 0; Xl.us[j] = 0; }
        const int d = r - c8;
        if (d >= 0 && d < 8){
            unsigned short h = f2bf(cN);
            Xh.us[d] = h;
            Xl.us[d] = f2bf(cN - bf2f(h));
        }
        const int idx = r*64 + (c8 ^ ((r&7)<<3));
        *(s16x8*)((unsigned short*)bufA + idx) = Xh.s;
        *(s16x8*)((unsigned short*)(bufA + 8192) + idx) = Xl.s;
        #pragma unroll
        for (int kt = 0; kt < 2; ++kt){
            const int ao = (16*rt + l15)*128 + ((kt*64 + 16*l4) ^ sw);
            Mh[kt] = *(const s16x8*)(bufC + ao);
            Ml[kt] = *(const s16x8*)(bufC + 8192 + ao);
        }
    }
    barrier_lds();

    // Newton-Schulz x12 (stored transposed; Minv symmetric)
    {
        char* pX = bufA; char* pY = bufB; char* pS = bufC;
        for (int it = 0; it < 12; ++it){
            #pragma unroll
            for (int ct = 0; ct < 2; ++ct){
                const int n = 16*(ct0+ct) + l15;
                f32x4 acc = {0.f,0.f,0.f,0.f};
                #pragma unroll
                for (int kt = 0; kt < 2; ++kt){
                    const int bo = n*128 + ((kt*64 + 16*l4) ^ sw);
                    s16x8 bh = *(const s16x8*)(pX + bo);
                    s16x8 bl = *(const s16x8*)(pX + 8192 + bo);
                    acc = mfma16(Mh[kt], bh, acc);
                    acc = mfma16(Mh[kt], bl, acc);
                    acc = mfma16(Ml[kt], bh, acc);
                }
                wr_hl(pY, n*128 + ((32*rt + 8*l4) ^ sw), acc);
            }
            barrier_lds();
            #pragma unroll
            for (int ct = 0; ct < 2; ++ct){
                const int n = 16*(ct0+ct) + l15;
                f32x4 acc = {0.f,0.f,0.f,0.f};
                #pragma unroll
                for (int kt = 0; kt < 2; ++kt){
                    const int ao = (16*rt + l15)*128 + ((kt*64 + 16*l4) ^ sw);
                    s16x8 ah = *(const s16x8*)(pY + ao);
                    s16x8 al = *(const s16x8*)(pY + 8192 + ao);
                    const int bo = n*128 + ((kt*64 + 16*l4) ^ sw);
                    s16x8 bh = *(const s16x8*)(pX + bo);
                    s16x8 bl = *(const s16x8*)(pX + 8192 + bo);
                    acc = mfma16(ah, bh, acc);
                    acc = mfma16(ah, bl, acc);
                    acc = mfma16(al, bh, acc);
                }
                const int xo = n*128 + ((32*rt + 8*l4) ^ sw);
                u32x2 H = *(const u32x2*)(pX + xo);
                u32x2 Lo = *(const u32x2*)(pX + 8192 + xo);
                f32x4 nx;
                #pragma unroll
                for (int r = 0; r < 4; ++r){
                    unsigned hu = (r < 2) ? H[0] : H[1];
                    unsigned lu = (r < 2) ? Lo[0] : Lo[1];
                    unsigned short hh = (unsigned short)((r & 1) ? (hu >> 16) : (hu & 0xffff));
                    unsigned short ll = (unsigned short)((r & 1) ? (lu >> 16) : (lu & 0xffff));
                    float xv = bf2f(hh) + bf2f(ll);
                    nx[r] = 2.0f * xv - acc[r];
                }
                wr_hl(pS, xo, nx);
            }
            barrier_lds();
            char* t = pX; pX = pS; pS = pY; pY = t;   // 12 iters -> X back in bufA
        }
    }

    // Mhi/Mlo -> ws, unswizzled linear [64][64]
    {
        unsigned short* mhi = (unsigned short*)(ws + WS_MHI);
        unsigned short* mlo = (unsigned short*)(ws + WS_MLO);
        const unsigned short* xh = (const unsigned short*)bufA;
        const unsigned short* xl = (const unsigned short*)(bufA + 8192);
        for (int i = tid; i < 4096; i += 512){
            int r = i >> 6, c = i & 63;
            int si = r*64 + (c ^ ((r&7)<<3));
            mhi[i] = xh[si];
            mlo[i] = xl[si];
        }
    }

    // W1MT = Minv @ W1^T via MFMA (A = X hi/lo swizzled in bufA, B = W1 rows) -> ws
    {
        const int h0 = w * 16;
        s16x8 fB0 = ldfrag_f32(W1 + (size_t)(h0+l15)*DIM + 8*l4);
        s16x8 fB1 = ldfrag_f32(W1 + (size_t)(h0+l15)*DIM + 32 + 8*l4);
        const unsigned short* xh = (const unsigned short*)bufA;
        const unsigned short* xl = (const unsigned short*)(bufA + 8192);
        unsigned short* w1mt = (unsigned short*)(ws + WS_W1MT);
        #pragma unroll
        for (int d0 = 0; d0 < 64; d0 += 16){
            f32x4 acc = {0.f,0.f,0.f,0.f};
            const int u0 = (d0+l15)*64 + ((8*l4) ^ ((l15&7)<<3));
            const int u1 = (d0+l15)*64 + ((32 + 8*l4) ^ ((l15&7)<<3));
            acc = mfma16(*(const s16x8*)&xh[u0], fB0, acc);
            acc = mfma16(*(const s16x8*)&xl[u0], fB0, acc);
            acc = mfma16(*(const s16x8*)&xh[u1], fB1, acc);
            acc = mfma16(*(const s16x8*)&xl[u1], fB1, acc);
            #pragma unroll
            for (int r = 0; r < 4; ++r)
                w1mt[(size_t)(d0 + 4*l4 + r)*HID + h0 + l15] = f2bf(acc[r]);
        }
    }
}

// ---------------- kernel 2: encoder + 64 leapfrog steps (R6 structure, 112 µs) ----------------
__global__ __launch_bounds__(TMAIN) void k_main(
    const float* __restrict__ z, const float* __restrict__ W1,
    const float* __restrict__ b1, const float* __restrict__ W2,
    const float* __restrict__ b2, const float* __restrict__ w3,
    const float* __restrict__ qW, const float* __restrict__ qb,
    const float* __restrict__ pW, const float* __restrict__ pb,
    const int* __restrict__ nsp, const char* __restrict__ ws,
    float* __restrict__ out)
{
    __shared__ __align__(16) char sQb_[ROWS*128], sPb_[ROWS*128];
    __shared__ __align__(16) char sA1_[ROWS*256], sG2_[ROWS*256], sG1_[ROWS*256];
    __shared__ __align__(16) char sD1_[ROWS*512];

    const int tid = threadIdx.x;
    const int w = tid >> 6, lane = tid & 63;
    const int l15 = lane & 15, l4 = lane >> 4;
    const int sw = (l15 & 7) << 4;
    const int m0 = w * 16;
    const int wq = w & 3;
    const int mq = wq * 16;
    const bool isQ = (w >= 4);
    const int NS = *nsp;
    const float dtv = 1.0f / (float)NS;   // T_SPAN = (0,1)
    const int TS = (NS + 1) * 128;
    const int b0 = blockIdx.x * ROWS;

    const unsigned short* wsW1MT = (const unsigned short*)(ws + WS_W1MT);
    const unsigned short* wsW1T  = (const unsigned short*)(ws + WS_W1T);
    const unsigned short* wsW2T  = (const unsigned short*)(ws + WS_W2T);
    const unsigned short* wsMhi  = (const unsigned short*)(ws + WS_MHI);
    const unsigned short* wsMlo  = (const unsigned short*)(ws + WS_MLO);

    s16x8 fW1[2], fW2[4], fW2T[4], fP4[4];
    #pragma unroll
    for (int kt = 0; kt < 2; ++kt)
        fW1[kt] = ldfrag_f32(W1 + (size_t)(m0+l15)*DIM + kt*32 + 8*l4);
    #pragma unroll
    for (int kt = 0; kt < 4; ++kt){
        fW2[kt]  = ldfrag_f32(W2 + (size_t)(m0+l15)*HID + kt*32 + 8*l4);
        fW2T[kt] = *(const s16x8*)&wsW2T[(m0+l15)*HID + kt*32 + 8*l4];
    }
    {
        const unsigned short* wp4 = isQ ? wsW1MT : wsW1T;
        #pragma unroll
        for (int kt = 0; kt < 4; ++kt)
            fP4[kt] = *(const s16x8*)&wp4[(mq+l15)*HID + kt*32 + 8*l4];
    }

    const f32x4 bb1 = *(const f32x4*)&b1[m0 + 4*l4];
    const f32x4 bb2 = *(const f32x4*)&b2[m0 + 4*l4];
    const f32x4 bw3 = *(const f32x4*)&w3[m0 + 4*l4];

    // ---- encoder: waves4-7 -> q0, waves0-3 -> p0 (masters in registers) ----
    f32x4 master;
    {
        const float* zr = z + (size_t)(b0 + l15) * DIM;
        s16x8 bz0 = ldfrag_f32(zr + 8*l4);
        s16x8 bz1 = ldfrag_f32(zr + 32 + 8*l4);
        const float* eW = isQ ? qW : pW;
        const float* eb = isQ ? qb : pb;
        const float* wr = eW + (size_t)(mq + l15) * DIM;
        s16x8 fE0 = ldfrag_f32(wr + 8*l4);
        s16x8 fE1 = ldfrag_f32(wr + 32 + 8*l4);
        f32x4 acc = {0.f,0.f,0.f,0.f};
        acc = mfma16(fE0, bz0, acc);
        acc = mfma16(fE1, bz1, acc);
        f32x4 be = *(const f32x4*)&eb[mq + 4*l4];
        master = acc + be;
        if (isQ){
            u32x2 pr; pr[0] = pk2(master[0],master[1]); pr[1] = pk2(master[2],master[3]);
            *(u32x2*)(sQb_ + l15*128 + ((32*wq + 8*l4) ^ sw)) = pr;
        }
        const int ofs = isQ ? (mq + 4*l4) : (64 + mq + 4*l4);
        *(f32x4*)(out + (size_t)(b0 + l15) * TS + ofs) = master;
    }
    barrier_lds();

    f32x4 vm = {0.f,0.f,0.f,0.f};
    f32x4 pend = {0.f,0.f,0.f,0.f};

    for (int t = 0; t <= NS; ++t){
        // ---- P1: deferred traj stores, then h1 = q@W1^T + b1 ----
        {
            if (t >= 1){
                if (isQ)
                    *(f32x4*)(out + (size_t)(b0+l15)*TS + (size_t)t*128 + mq + 4*l4) = pend;
                else if (t >= 2)
                    *(f32x4*)(out + (size_t)(b0+l15)*TS + (size_t)(t-1)*128 + 64 + mq + 4*l4) = pend;
            }
            s16x8 bq0 = *(const s16x8*)(sQb_ + l15*128 + ((16*l4) ^ sw));
            s16x8 bq1 = *(const s16x8*)(sQb_ + l15*128 + ((64 + 16*l4) ^ sw));
            f32x4 a0 = {0.f,0.f,0.f,0.f}, a1v = {0.f,0.f,0.f,0.f};
            a0 = mfma16(fW1[0], bq0, a0);
            a1v = mfma16(fW1[1], bq1, a1v);
            f32x4 si, dv;
            #pragma unroll
            for (int r = 0; r < 4; ++r){
                float h = a0[r] + a1v[r] + bb1[r];
                float sg = 1.0f / (1.0f + __expf(-h));
                float s = h * sg;
                si[r] = s;
                dv[r] = sg + s * (1.0f - sg);
            }
            u32x2 pr; pr[0] = pk2(si[0],si[1]); pr[1] = pk2(si[2],si[3]);
            *(u32x2*)(sA1_ + l15*256 + ((2*m0 + 8*l4) ^ sw)) = pr;
            *(f32x4*)(sD1_ + l15*512 + ((4*m0 + 16*l4) ^ sw)) = dv;
        }
        barrier_lds();
        // ---- P2: h2 = a1@W2^T + b2 ; g2 = w3 * silu'(h2) ----
        {
            f32x4 a0 = {0.f,0.f,0.f,0.f}, a1v = {0.f,0.f,0.f,0.f};
            #pragma unroll
            for (int kt = 0; kt < 2; ++kt){
                s16x8 ba0 = *(const s16x8*)(sA1_ + l15*256 + ((64*(2*kt) + 16*l4) ^ sw));
                s16x8 ba1 = *(const s16x8*)(sA1_ + l15*256 + ((64*(2*kt+1) + 16*l4) ^ sw));
                a0 = mfma16(fW2[2*kt], ba0, a0);
                a1v = mfma16(fW2[2*kt+1], ba1, a1v);
            }
            f32x4 g2;
            #pragma unroll
            for (int r = 0; r < 4; ++r){
                float h = a0[r] + a1v[r] + bb2[r];
                float sg = 1.0f / (1.0f + __expf(-h));
                g2[r] = bw3[r] * (sg * (1.0f + h * (1.0f - sg)));
            }
            u32x2 pr; pr[0] = pk2(g2[0],g2[1]); pr[1] = pk2(g2[2],g2[3]);
            *(u32x2*)(sG2_ + l15*256 + ((2*m0 + 8*l4) ^ sw)) = pr;
        }
        barrier_lds();
        // ---- P3: g1 = (g2 @ W2) * d1 ----
        {
            f32x4 a0 = {0.f,0.f,0.f,0.f}, a1v = {0.f,0.f,0.f,0.f};
            #pragma unroll
            for (int kt = 0; kt < 2; ++kt){
                s16x8 bg0 = *(const s16x8*)(sG2_ + l15*256 + ((64*(2*kt) + 16*l4) ^ sw));
                s16x8 bg1 = *(const s16x8*)(sG2_ + l15*256 + ((64*(2*kt+1) + 16*l4) ^ sw));
                a0 = mfma16(fW2T[2*kt], bg0, a0);
                a1v = mfma16(fW2T[2*kt+1], bg1, a1v);
            }
            f32x4 dv = *(const f32x4*)(sD1_ + l15*512 + ((4*m0 + 16*l4) ^ sw));
            f32x4 g1;
            #pragma unroll
            for (int r = 0; r < 4; ++r) g1[r] = (a0[r] + a1v[r]) * dv[r];
            u32x2 pr; pr[0] = pk2(g1[0],g1[1]); pr[1] = pk2(g1[2],g1[3]);
            *(u32x2*)(sG1_ + l15*256 + ((2*m0 + 8*l4) ^ sw)) = pr;
        }
        barrier_lds();
        // ---- P4: w<4: grad=g1@W1T -> p; w>=4: wv=g1@W1MT -> v,q ----
        if (!isQ){
            f32x4 a0 = {0.f,0.f,0.f,0.f}, a1v = {0.f,0.f,0.f,0.f};
            #pragma unroll
            for (int kt = 0; kt < 2; ++kt){
                s16x8 bg0 = *(const s16x8*)(sG1_ + l15*256 + ((64*(2*kt) + 16*l4) ^ sw));
                s16x8 bg1 = *(const s16x8*)(sG1_ + l15*256 + ((64*(2*kt+1) + 16*l4) ^ sw));
                a0 = mfma16(fP4[2*kt], bg0, a0);
                a1v = mfma16(fP4[2*kt+1], bg1, a1v);
            }
            if (t == 0){
                #pragma unroll
                for (int r = 0; r < 4; ++r) master[r] -= 0.5f * dtv * (a0[r] + a1v[r]);
                u32x2 pr; pr[0] = pk2(master[0],master[1]); pr[1] = pk2(master[2],master[3]);
                *(u32x2*)(sPb_ + l15*128 + ((32*wq + 8*l4) ^ sw)) = pr;
            } else {
                #pragma unroll
                for (int r = 0; r < 4; ++r){
                    float g = a0[r] + a1v[r];
                    pend[r] = master[r] - 0.5f * dtv * g;   // p(t)
                    master[r] -= dtv * g;                    // p_half(t+1/2)
                }
            }
        } else if (t >= 1){
            f32x4 a0 = {0.f,0.f,0.f,0.f}, a1v = {0.f,0.f,0.f,0.f};
            #pragma unroll
            for (int kt = 0; kt < 2; ++kt){
                s16x8 bg0 = *(const s16x8*)(sG1_ + l15*256 + ((64*(2*kt) + 16*l4) ^ sw));
                s16x8 bg1 = *(const s16x8*)(sG1_ + l15*256 + ((64*(2*kt+1) + 16*l4) ^ sw));
                a0 = mfma16(fP4[2*kt], bg0, a0);
                a1v = mfma16(fP4[2*kt+1], bg1, a1v);
            }
            #pragma unroll
            for (int r = 0; r < 4; ++r){
                vm[r] -= dtv * (a0[r] + a1v[r]);   // v(t+1/2)
                master[r] += dtv * vm[r];          // q(t+1)
            }
            u32x2 pr; pr[0] = pk2(master[0],master[1]); pr[1] = pk2(master[2],master[3]);
            *(u32x2*)(sQb_ + l15*128 + ((32*wq + 8*l4) ^ sw)) = pr;
            pend = master;
        }
        barrier_lds();
        // ---- one-time v init after the first half-kick ----
        if (t == 0){
            if (isQ){
                s16x8 fMhi[2], fMlo[2];
                #pragma unroll
                for (int kt = 0; kt < 2; ++kt){
                    fMhi[kt] = *(const s16x8*)&wsMhi[(mq+l15)*DIM + kt*32 + 8*l4];
                    fMlo[kt] = *(const s16x8*)&wsMlo[(mq+l15)*DIM + kt*32 + 8*l4];
                }
                s16x8 bp0 = *(const s16x8*)(sPb_ + l15*128 + ((16*l4) ^ sw));
                s16x8 bp1 = *(const s16x8*)(sPb_ + l15*128 + ((64 + 16*l4) ^ sw));
                f32x4 aH = {0.f,0.f,0.f,0.f}, aL = {0.f,0.f,0.f,0.f};
                aH = mfma16(fMhi[0], bp0, aH);
                aH = mfma16(fMhi[1], bp1, aH);
                aL = mfma16(fMlo[0], bp0, aL);
                aL = mfma16(fMlo[1], bp1, aL);
                #pragma unroll
                for (int r = 0; r < 4; ++r){
                    vm[r] = aH[r] + aL[r];         // v(1/2)
                    master[r] += dtv * vm[r];      // q(1)
                }
                u32x2 pr; pr[0] = pk2(master[0],master[1]); pr[1] = pk2(master[2],master[3]);
                *(u32x2*)(sQb_ + l15*128 + ((32*wq + 8*l4) ^ sw)) = pr;
                pend = master;
            }
            barrier_lds();
        }
    }
    // flush last p-traj
    if (!isQ)
        *(f32x4*)(out + (size_t)(b0+l15)*TS + (size_t)NS*128 + 64 + mq + 4*l4) = pend;
}

extern "C" void kernel_launch(void* const* d_in, const int* in_sizes, int n_in,
                              void* d_out, int out_size, void* d_ws, size_t ws_size,
                              hipStream_t stream)
{
    const float* z  = (const float*)d_in[0];
    const float* L  = (const float*)d_in[1];
    const float* W1 = (const float*)d_in[2];
    const float* b1 = (const float*)d_in[3];
    const float* W2 = (const float*)d_in[4];
    const float* b2 = (const float*)d_in[5];
    const float* w3 = (const float*)d_in[6];
    // d_in[7] = Vb3: constant, vanishes in gradV
    const float* qW = (const float*)d_in[8];
    const float* qb = (const float*)d_in[9];
    const float* pW = (const float*)d_in[10];
    const float* pb = (const float*)d_in[11];
    const int* nsp  = (const int*)d_in[12];
    float* out = (float*)d_out;
    char* ws = (char*)d_ws;
    const int B = in_sizes[0] / DIM;

    k_prep<<<2, 512, 0, stream>>>(L, W1, W2, ws);
    k_main<<<B/ROWS, TMAIN, 0, stream>>>(z, W1, b1, W2, b2, w3, qW, qb, pW, pb, nsp, ws, out);
}